// Round 3
// baseline (855.205 us; speedup 1.0000x reference)
//
#include <hip/hip_runtime.h>

// ---------------- problem constants ----------------
#define NB    2
#define QLEN  512
#define HIDD  5120
#define QLORA 1536
#define NHEAD 128
#define QHD   192
#define VHD   128
#define KVTOT 1024

typedef float          f32x4   __attribute__((ext_vector_type(4)));
typedef __bf16         bf16x8  __attribute__((ext_vector_type(8)));
typedef unsigned short u16x8   __attribute__((ext_vector_type(8)));
typedef unsigned short u16x4   __attribute__((ext_vector_type(4)));

static __device__ __forceinline__ unsigned short f2bf(float f) {
  union { float f; unsigned u; } v; v.f = f;
  return (unsigned short)((v.u + 0x7fffu + ((v.u >> 16) & 1u)) >> 16);
}

static __device__ __forceinline__ void g2l16(const void* g, void* l) {
  __builtin_amdgcn_global_load_lds(
      (const __attribute__((address_space(1))) void*)g,
      (__attribute__((address_space(3))) void*)l, 16, 0, 0);
}

// ---------------- merged f32 -> bf16 converts (5 segments) ----------------
struct CvtArgs {
  const float* src[5];
  unsigned short* dst[5];
  int off[6];  // cumulative block offsets; each block = 1024 f32x4
};

__global__ __launch_bounds__(256) void cvt_all_k(CvtArgs a) {
  int b = blockIdx.x, s = 0;
  #pragma unroll
  for (int k = 0; k < 4; ++k) if (b >= a.off[k + 1]) s = k + 1;
  long lb = b - a.off[s];
  const float* in = a.src[s];
  unsigned short* out = a.dst[s];
  long base = lb * 1024 + threadIdx.x;
  #pragma unroll
  for (int k = 0; k < 4; ++k) {
    long i = base + k * 256;
    f32x4 v = *(const f32x4*)(in + i * 4);
    u16x4 o;
    o[0] = f2bf(v[0]); o[1] = f2bf(v[1]); o[2] = f2bf(v[2]); o[3] = f2bf(v[3]);
    *(u16x4*)(out + i * 4) = o;
  }
}

// ---------------- mask zero-flags: 1 flag per (b, 128-qtile, 64-ktile) ----------------
__global__ __launch_bounds__(256) void flags_k(const float* __restrict__ mask,
                                               int* __restrict__ flags) {
  int id = blockIdx.x;  // b*64 + qt*16 + kt
  int b = id >> 6, qt = (id >> 4) & 3, kt = id & 15;
  const float* base = mask + (long)b * 524288 + (long)qt * 128 * 1024 + kt * 64;
  int t = threadIdx.x, w = t >> 6;
  unsigned acc = 0;
  #pragma unroll
  for (int i = 0; i < 32; ++i) {
    int e = i * 256 + t;
    int r = e >> 6, c = e & 63;
    union { float f; unsigned u; } v; v.f = base[(long)r * 1024 + c];
    acc |= v.u;
  }
  int any = __any(acc != 0);
  __shared__ int sf[4];
  if ((t & 63) == 0) sf[w] = any;
  __syncthreads();
  if (t == 0) flags[id] = sf[0] | sf[1] | sf[2] | sf[3];
}

// ---------------- fused q_a + ckv GEMM, split-K(4): 128x64 tile, 4 waves ----------------
// B = [w_q_a (1536 rows) ; w_kv_a (576 rows) ; 64 zero rows], rows K-contig.
// writes f32 partials: part[(z*1024 + row)*2176 + col]
__global__ __launch_bounds__(256) void gemm_qa_ckv(const unsigned short* __restrict__ A,
                                                   const unsigned short* __restrict__ Bm,
                                                   float* __restrict__ part) {
  __shared__ __align__(16) unsigned short sA[128 * 64];
  __shared__ __align__(16) unsigned short sB[64 * 64];
  const int t = threadIdx.x, w = t >> 6, l = t & 63;
  const int l15 = l & 15, lh = l >> 4;
  const int mb = blockIdx.y, nb = blockIdx.x, z = blockIdx.z;
  const unsigned short* Ab = A + (long)mb * 128 * HIDD;
  const unsigned short* Bb = Bm + (long)nb * 64 * HIDD;
  f32x4 acc[2][4];
  #pragma unroll
  for (int i = 0; i < 2; ++i)
    #pragma unroll
    for (int j = 0; j < 4; ++j)
      #pragma unroll
      for (int r = 0; r < 4; ++r) acc[i][j][r] = 0.f;

  const int k0 = z * 1280;
  for (int kt = k0; kt < k0 + 1280; kt += 64) {
    #pragma unroll
    for (int i2 = 0; i2 < 4; ++i2) {
      int n = i2 * 256 + t, r = n >> 3, c = n & 7;
      g2l16(Ab + (long)r * HIDD + kt + c * 8, (char*)sA + (i2 * 256 + w * 64) * 16);
    }
    #pragma unroll
    for (int i2 = 0; i2 < 2; ++i2) {
      int n = i2 * 256 + t, r = n >> 3, c = n & 7;
      g2l16(Bb + (long)r * HIDD + kt + c * 8, (char*)sB + (i2 * 256 + w * 64) * 16);
    }
    __syncthreads();
    #pragma unroll
    for (int ks = 0; ks < 2; ++ks) {
      bf16x8 af[2], bfr[4];
      #pragma unroll
      for (int i = 0; i < 2; ++i)
        af[i] = *(const bf16x8*)(sA + (w * 32 + i * 16 + l15) * 64 + ks * 32 + lh * 8);
      #pragma unroll
      for (int j = 0; j < 4; ++j)
        bfr[j] = *(const bf16x8*)(sB + (j * 16 + l15) * 64 + ks * 32 + lh * 8);
      #pragma unroll
      for (int i = 0; i < 2; ++i)
        #pragma unroll
        for (int j = 0; j < 4; ++j)
          acc[i][j] = __builtin_amdgcn_mfma_f32_16x16x32_bf16(af[i], bfr[j], acc[i][j], 0, 0, 0);
    }
    __syncthreads();
  }
  float* po = part + (long)z * 1024 * 2176;
  const int colbase = nb * 64;
  #pragma unroll
  for (int i = 0; i < 2; ++i)
    #pragma unroll
    for (int j = 0; j < 4; ++j) {
      const int col = colbase + j * 16 + l15;
      #pragma unroll
      for (int r4 = 0; r4 < 4; ++r4) {
        const long row = (long)mb * 128 + w * 32 + i * 16 + lh * 4 + r4;
        po[row * 2176 + col] = acc[i][j][r4];
      }
    }
}

// ---------------- fused rmsnorm(q_a) + rmsnorm(ckv) + k_pe broadcast ----------------
__global__ __launch_bounds__(256) void post_a_k(const float* __restrict__ part,
                                                const float* __restrict__ gq,
                                                const float* __restrict__ gkv,
                                                unsigned short* __restrict__ qan,
                                                unsigned short* __restrict__ ckvn,
                                                float* __restrict__ kout,
                                                unsigned short* __restrict__ kb) {
  const long ZS = 1024L * 2176;
  int bid = blockIdx.x, t = threadIdx.x;
  if (bid >= 2048) {  // k_pe broadcast
    int row = bid - 2048;
    int j = t & 63, h0 = t >> 6;
    const float* p = part + (long)row * 2176 + 2048 + j;
    float v = p[0] + p[ZS] + p[2 * ZS] + p[3 * ZS];
    unsigned short vb = f2bf(v);
    long b_ = row >> 9, qi = row & 511;
    for (int h = h0; h < NHEAD; h += 4) {
      long idx = ((b_ * NHEAD + h) * KVTOT + 512 + qi) * QHD + 128 + j;
      kout[idx] = v;
      kb[idx] = vb;
    }
    return;
  }
  bool isQ = bid < 1024;
  int row = isQ ? bid : bid - 1024;
  int cols = isQ ? 1536 : 512;
  const float* g = isQ ? gq : gkv;
  unsigned short* out = isQ ? (qan + (long)row * 1536) : (ckvn + (long)row * 512);
  const float* x = part + (long)row * 2176 + (isQ ? 0 : 1536);
  int w = t >> 6, l = t & 63;
  float xv[6];
  int nc = cols >> 8;
  float ss = 0.f;
  for (int i = 0; i < nc; ++i) {
    int c = t + i * 256;
    float v = x[c] + x[c + ZS] + x[c + 2 * ZS] + x[c + 3 * ZS];
    xv[i] = v; ss += v * v;
  }
  #pragma unroll
  for (int m = 32; m >= 1; m >>= 1) ss += __shfl_xor(ss, m);
  __shared__ float red[4];
  if (l == 0) red[w] = ss;
  __syncthreads();
  float tot = red[0] + red[1] + red[2] + red[3];
  float rs = rsqrtf(tot / (float)cols + 1e-6f);
  for (int i = 0; i < nc; ++i) {
    int c = t + i * 256;
    out[c] = f2bf(g[c] * xv[i] * rs);
  }
}

// ---------------- merged Q-GEMM + KV-GEMM: 128x128 tile, BK=64, 4 waves ----------------
// x < 192: Q GEMM (A=qan,B=wqb,K=1536) -> q_bf [b][h][qi][192]
// x >= 192: KV GEMM (A=ckvn,B=wkvb,K=512) -> key f32+bf16 / value f32 (new rows)
__global__ __launch_bounds__(256) void gemm_bt2(const unsigned short* __restrict__ Aq,
                                                const unsigned short* __restrict__ Bq,
                                                const unsigned short* __restrict__ Akv,
                                                const unsigned short* __restrict__ Bkv,
                                                unsigned short* __restrict__ qout,
                                                float* __restrict__ kout,
                                                float* __restrict__ vout,
                                                unsigned short* __restrict__ kb) {
  __shared__ __align__(16) unsigned short sA[128 * 64];
  __shared__ __align__(16) unsigned short sB[128 * 64];
  const int t = threadIdx.x, w = t >> 6, l = t & 63;
  const int l15 = l & 15, lh = l >> 4;
  const int wm = w >> 1, wn = w & 1;
  const bool isQ = blockIdx.x < 192;
  const int nb = isQ ? blockIdx.x : blockIdx.x - 192;
  const int mb = blockIdx.y;
  const int K = isQ ? QLORA : 512;
  const unsigned short* Ab = (isQ ? Aq : Akv) + (long)mb * 128 * K;
  const unsigned short* Bb = (isQ ? Bq : Bkv) + (long)nb * 128 * K;
  f32x4 acc[4][4];
  #pragma unroll
  for (int i = 0; i < 4; ++i)
    #pragma unroll
    for (int j = 0; j < 4; ++j)
      #pragma unroll
      for (int r = 0; r < 4; ++r) acc[i][j][r] = 0.f;

  const int srow = l >> 3;
  const int scol = (l & 7) * 8;

  for (int kt = 0; kt < K; kt += 64) {
    #pragma unroll
    for (int i = 0; i < 4; ++i) {
      const int chunk = i * 4 + w;
      const int r = chunk * 8 + srow;
      g2l16(Ab + (long)r * K + kt + scol, (char*)sA + chunk * 1024);
      g2l16(Bb + (long)r * K + kt + scol, (char*)sB + chunk * 1024);
    }
    __syncthreads();
    #pragma unroll
    for (int ks = 0; ks < 2; ++ks) {
      bf16x8 af[4], bfr[4];
      #pragma unroll
      for (int i = 0; i < 4; ++i)
        af[i] = *(const bf16x8*)(sA + (wm * 64 + i * 16 + l15) * 64 + ks * 32 + lh * 8);
      #pragma unroll
      for (int j = 0; j < 4; ++j)
        bfr[j] = *(const bf16x8*)(sB + (wn * 64 + j * 16 + l15) * 64 + ks * 32 + lh * 8);
      #pragma unroll
      for (int i = 0; i < 4; ++i)
        #pragma unroll
        for (int j = 0; j < 4; ++j)
          acc[i][j] = __builtin_amdgcn_mfma_f32_16x16x32_bf16(af[i], bfr[j], acc[i][j], 0, 0, 0);
    }
    __syncthreads();
  }

  const long rowbase = (long)mb * 128 + wm * 64;
  const int colbase = nb * 128 + wn * 64;
  #pragma unroll
  for (int i = 0; i < 4; ++i) {
    #pragma unroll
    for (int j = 0; j < 4; ++j) {
      const int col = colbase + j * 16 + l15;
      #pragma unroll
      for (int r4 = 0; r4 < 4; ++r4) {
        const long row = rowbase + i * 16 + lh * 4 + r4;
        const float v = acc[i][j][r4];
        const long b_ = row >> 9, qi = row & 511;
        if (isQ) {
          const int h = col / QHD, d = col - h * QHD;
          qout[(((b_ * NHEAD + h) * QLEN + qi)) * QHD + d] = f2bf(v);
        } else {
          const int h = col >> 8, d = col & 255;
          if (d < 128) {
            const long idx = ((b_ * NHEAD + h) * KVTOT + 512 + qi) * QHD + d;
            kout[idx] = v;
            kb[idx] = f2bf(v);
          } else {
            vout[((b_ * NHEAD + h) * KVTOT + 512 + qi) * VHD + (d - 128)] = v;
          }
        }
      }
    }
  }
}

// ---------------- past key copy: f32 out + bf16 ws ----------------
__global__ __launch_bounds__(256) void copy_key_past_k(const float* __restrict__ pk,
                                                       float* __restrict__ kout,
                                                       unsigned short* __restrict__ kb) {
  long i4 = (long)blockIdx.x * 256 + threadIdx.x;
  f32x4 v = *(const f32x4*)(pk + i4 * 4);
  long e = i4 * 4;
  long bh = e / 98304;
  long rem = e - bh * 98304;
  long oidx = bh * 196608 + rem;
  *(f32x4*)(kout + oidx) = v;
  u16x4 b;
  b[0] = f2bf(v[0]); b[1] = f2bf(v[1]); b[2] = f2bf(v[2]); b[3] = f2bf(v[3]);
  *(u16x4*)(kb + oidx) = b;
}

// ---------------- fused V: past copy (pv->out_val) + full transpose -> Vt bf16 ----------------
__global__ __launch_bounds__(256) void vfix_k(const float* __restrict__ pv,
                                              float* __restrict__ outv,
                                              unsigned short* __restrict__ vt) {
  __shared__ __align__(16) unsigned short sT[128 * 72];
  int bh = blockIdx.x >> 4, kt = blockIdx.x & 15;
  int t = threadIdx.x;
  const float* src = (kt < 8) ? pv + ((long)bh * 512 + kt * 64) * VHD
                              : outv + ((long)bh * KVTOT + kt * 64) * VHD;
  float* dstv = outv + ((long)bh * KVTOT + kt * 64) * VHD;
  #pragma unroll
  for (int i = 0; i < 8; ++i) {
    int id = t + i * 256;
    int r = id >> 5, c4 = (id & 31) * 4;
    f32x4 v = *(const f32x4*)(src + (long)r * VHD + c4);
    if (kt < 8) *(f32x4*)(dstv + (long)r * VHD + c4) = v;
    #pragma unroll
    for (int jj = 0; jj < 4; ++jj) sT[(c4 + jj) * 72 + r] = f2bf(v[jj]);
  }
  __syncthreads();
  #pragma unroll
  for (int i = 0; i < 4; ++i) {
    int id = t + i * 256;
    int d = id >> 3, c = id & 7;
    u16x8 v = *(const u16x8*)(sT + d * 72 + c * 8);
    *(u16x8*)(vt + ((long)bh * VHD + d) * KVTOT + kt * 64 + c * 8) = v;
  }
}

// ---------------- K-tile staging: XOR-swizzled source, linear LDS dest (512 thr) ----------
static __device__ __forceinline__ void stage_k512(const unsigned short* __restrict__ src,
                                                  char* dstbase, int t) {
  #pragma unroll
  for (int i2 = 0; i2 < 3; ++i2) {
    int n = i2 * 512 + t;
    int r = n / 24, cp = n - r * 24;
    int c = cp ^ (r & 7);
    g2l16(src + (long)r * QHD + c * 8, dstbase + n * 16);
  }
}

// ---------------- flash attention: 1 block = (b,h, 128-q tile), 8 waves x 16 rows ------
// LDS: K dbuf 48KB + sP 17KB = 66.5KB -> 2 blocks/CU (16 waves). 1 barrier/iter.
__global__ __launch_bounds__(512, 4) void attn_k(const unsigned short* __restrict__ Qw,
                                                 const unsigned short* __restrict__ Kb,
                                                 const unsigned short* __restrict__ Vt,
                                                 const float* __restrict__ mask,
                                                 const int* __restrict__ flags,
                                                 float* __restrict__ outp) {
  __shared__ __align__(16) unsigned short sK[2][64 * 192];
  __shared__ __align__(16) unsigned short sP[128 * 68];
  const int t = threadIdx.x, w = t >> 6, l = t & 63;
  const int l15 = l & 15, lh = l >> 4;
  // XCD-grouping remap: the 4 q-tiles of one bh -> same XCD, consecutive slots.
  const int raw = blockIdx.x;
  const int xcd = raw & 7, slot = raw >> 3;
  const int bh = xcd * 32 + (slot >> 2), qt = slot & 3;
  const long b_ = bh >> 7;
  const float SCALE = 0.051023330039633184f;
  const int swz = l15 & 7;

  const int qrow0 = qt * 128 + w * 16;
  const unsigned short* Kbh = Kb + (long)bh * KVTOT * QHD;
  const unsigned short* Qb = Qw + ((long)bh * QLEN + qrow0 + l15) * QHD + lh * 8;
  const unsigned short* Vl = Vt + ((long)bh * VHD + l15) * KVTOT + lh * 8;
  const float* mrow = mask + b_ * 524288 + (long)(qrow0 + lh * 4) * 1024 + l15;
  const int fbase = (int)b_ * 64 + qt * 16;

  bf16x8 qf[6];
  #pragma unroll
  for (int ks = 0; ks < 6; ++ks) qf[ks] = *(const bf16x8*)(Qb + ks * 32);

  f32x4 o[8];
  #pragma unroll
  for (int j = 0; j < 8; ++j)
    #pragma unroll
    for (int r = 0; r < 4; ++r) o[j][r] = 0.f;
  float m_[4], l_[4];
  #pragma unroll
  for (int r = 0; r < 4; ++r) { m_[r] = -1e30f; l_[r] = 0.f; }

  stage_k512(Kbh, (char*)sK[0], t);
  __syncthreads();

  for (int kt = 0; kt < 16; ++kt) {
    const int cur = kt & 1;
    if (kt < 15) stage_k512(Kbh + (long)(kt + 1) * 64 * QHD, (char*)sK[cur ^ 1], t);
    const int flag = flags[fbase + kt];

    // S = Q K^T  (swizzled sK reads)
    const unsigned short* sKc = sK[cur];
    f32x4 s[4];
    #pragma unroll
    for (int j = 0; j < 4; ++j)
      #pragma unroll
      for (int r = 0; r < 4; ++r) s[j][r] = 0.f;
    #pragma unroll
    for (int j = 0; j < 4; ++j)
      #pragma unroll
      for (int ks = 0; ks < 6; ++ks) {
        bf16x8 kf = *(const bf16x8*)(sKc + ((j * 16 + l15) * 24 + ((ks * 4 + lh) ^ swz)) * 8);
        s[j] = __builtin_amdgcn_mfma_f32_16x16x32_bf16(qf[ks], kf, s[j], 0, 0, 0);
      }

    // online softmax (rows = qrow0 + lh*4 + rg), deferred sum reduce
    u16x4 pk16[4];
    #pragma unroll
    for (int rg = 0; rg < 4; ++rg) {
      float sc[4];
      if (flag) {
        #pragma unroll
        for (int j = 0; j < 4; ++j)
          sc[j] = s[j][rg] * SCALE + mrow[(long)rg * 1024 + kt * 64 + j * 16];
      } else {
        #pragma unroll
        for (int j = 0; j < 4; ++j) sc[j] = s[j][rg] * SCALE;
      }
      float mx = fmaxf(fmaxf(sc[0], sc[1]), fmaxf(sc[2], sc[3]));
      mx = fmaxf(mx, __shfl_xor(mx, 1));
      mx = fmaxf(mx, __shfl_xor(mx, 2));
      mx = fmaxf(mx, __shfl_xor(mx, 4));
      mx = fmaxf(mx, __shfl_xor(mx, 8));
      float mo = m_[rg];
      float mn = fmaxf(mo, mx);
      if (__any(mn > mo)) {
        float al = __expf(mo - mn);
        #pragma unroll
        for (int jj = 0; jj < 8; ++jj) o[jj][rg] *= al;
        l_[rg] *= al;
        m_[rg] = mn;
      }
      float ps = 0.f;
      #pragma unroll
      for (int j = 0; j < 4; ++j) {
        float p = __expf(sc[j] - m_[rg]);
        ps += p;
        pk16[rg][j] = f2bf(p);
      }
      l_[rg] += ps;
    }

    // P write: wave-local rows [w*16, w*16+16) — no barrier needed around it
    #pragma unroll
    for (int rg = 0; rg < 4; ++rg) {
      const int prow = w * 16 + lh * 4 + rg;
      #pragma unroll
      for (int j = 0; j < 4; ++j)
        sP[prow * 68 + j * 16 + l15] = pk16[rg][j];
    }

    // O += P V  (P wave-local from sP; V direct from global, L2-resident)
    #pragma unroll
    for (int ks = 0; ks < 2; ++ks) {
      bf16x8 pf = *(const bf16x8*)(sP + (w * 16 + l15) * 68 + ks * 32 + lh * 8);
      #pragma unroll
      for (int jj = 0; jj < 8; ++jj) {
        bf16x8 vf = *(const bf16x8*)(Vl + (long)jj * 16 * KVTOT + kt * 64 + ks * 32);
        o[jj] = __builtin_amdgcn_mfma_f32_16x16x32_bf16(pf, vf, o[jj], 0, 0, 0);
      }
    }
    __syncthreads();  // end of iter: QK reads done before next stage overwrite; drains stage
  }

  #pragma unroll
  for (int rg = 0; rg < 4; ++rg) {
    float ls = l_[rg];
    ls += __shfl_xor(ls, 1);
    ls += __shfl_xor(ls, 2);
    ls += __shfl_xor(ls, 4);
    ls += __shfl_xor(ls, 8);
    float inv = 1.0f / ls;
    long row = (long)bh * QLEN + qrow0 + lh * 4 + rg;
    #pragma unroll
    for (int jj = 0; jj < 8; ++jj)
      outp[row * VHD + jj * 16 + l15] = o[jj][rg] * inv;
  }
}

// ---------------- workspace layout (bytes) ----------------
#define WS_HID_BF   0L           // 1024x5120 bf16            = 10,485,760
#define WS_WQA_BF   10485760L    // stacked [wqa;wkva;pad] 2176x5120 bf16 = 22,282,240
#define WS_WQB_BF   32768000L    // 24576x1536 bf16           = 75,497,472
#define WS_WKVB_BF  108265472L   // 32768x512 bf16            = 33,554,432
#define WS_QAN_BF   141819904L   // 1024x1536 bf16            =  3,145,728
#define WS_CKVN_BF  144965632L   // 1024x512 bf16             =  1,048,576
#define WS_Q_BF     146014208L   // 50,331,648 (part f32 35.6MB aliased here first)
#define WS_KB_BF    196345856L   // 100,663,296
#define WS_VT_BF    297009152L   // 67,108,864
#define WS_FLAGS    364118016L   // 512
// total ~364.1 MB (< previously-working 373 MB)

extern "C" void kernel_launch(void* const* d_in, const int* in_sizes, int n_in,
                              void* d_out, int out_size, void* d_ws, size_t ws_size,
                              hipStream_t stream) {
  const float* hs   = (const float*)d_in[0];
  const float* mask = (const float*)d_in[1];
  const float* pk   = (const float*)d_in[2];
  const float* pv   = (const float*)d_in[3];
  const float* wqa  = (const float*)d_in[4];
  const float* gqa  = (const float*)d_in[5];
  const float* wqb  = (const float*)d_in[6];
  const float* wkva = (const float*)d_in[7];
  const float* gkva = (const float*)d_in[8];
  const float* wkvb = (const float*)d_in[9];

  char* ws = (char*)d_ws;
  unsigned short* hid_bf  = (unsigned short*)(ws + WS_HID_BF);
  unsigned short* wqa_bf  = (unsigned short*)(ws + WS_WQA_BF);  // stacked [wqa;wkva;pad]
  unsigned short* wkva_bf = wqa_bf + (long)1536 * 5120;
  unsigned short* wqb_bf  = (unsigned short*)(ws + WS_WQB_BF);
  unsigned short* wkvb_bf = (unsigned short*)(ws + WS_WKVB_BF);
  unsigned short* qan_bf  = (unsigned short*)(ws + WS_QAN_BF);
  unsigned short* ckvn_bf = (unsigned short*)(ws + WS_CKVN_BF);
  unsigned short* q_bf    = (unsigned short*)(ws + WS_Q_BF);
  float*          part    = (float*)(ws + WS_Q_BF);  // aliased: dead before q_bf written
  unsigned short* kb_bf   = (unsigned short*)(ws + WS_KB_BF);
  unsigned short* vt_bf   = (unsigned short*)(ws + WS_VT_BF);
  int*            flags   = (int*)(ws + WS_FLAGS);

  float* out_attn = (float*)d_out;
  float* out_key  = (float*)d_out + 16777216;
  float* out_val  = (float*)d_out + 67108864;

  // 0. mask zero-flags
  flags_k<<<128, 256, 0, stream>>>(mask, flags);
  // 1. zero the 64 pad rows of stacked wkva, then all converts in one kernel
  hipMemsetAsync(ws + WS_WQA_BF + (long)2112 * 5120 * 2, 0, (long)64 * 5120 * 2, stream);
  CvtArgs ca;
  ca.src[0] = hs;     ca.dst[0] = hid_bf;
  ca.src[1] = wqa;    ca.dst[1] = wqa_bf;
  ca.src[2] = wkva;   ca.dst[2] = wkva_bf;
  ca.src[3] = wqb;    ca.dst[3] = wqb_bf;
  ca.src[4] = wkvb;   ca.dst[4] = wkvb_bf;
  ca.off[0] = 0; ca.off[1] = 1280; ca.off[2] = 3200; ca.off[3] = 3920;
  ca.off[4] = 13136; ca.off[5] = 17232;
  cvt_all_k<<<17232, 256, 0, stream>>>(ca);
  // 2. past key copy (independent)
  copy_key_past_k<<<24576, 256, 0, stream>>>(pk, out_key, kb_bf);
  // 3. fused q_a + ckv GEMM, split-K(4) -> part
  gemm_qa_ckv<<<dim3(34, 8, 4), 256, 0, stream>>>(hid_bf, wqa_bf, part);
  // 4. fused rmsnorms + k_pe broadcast (sums partials)
  post_a_k<<<3072, 256, 0, stream>>>(part, gqa, gkva, qan_bf, ckvn_bf, out_key, kb_bf);
  // 5. merged Q-GEMM + KV-GEMM (q_bf overwrites part — safe, part is dead)
  gemm_bt2<<<dim3(448, 8), 256, 0, stream>>>(qan_bf, wqb_bf, ckvn_bf, wkvb_bf,
                                             q_bf, out_key, out_val, kb_bf);
  // 6. fused V past-copy + transpose -> Vt bf16
  vfix_k<<<4096, 256, 0, stream>>>(pv, out_val, vt_bf);
  // 7. attention
  attn_k<<<1024, 512, 0, stream>>>(q_bf, kb_bf, vt_bf, mask, flags, out_attn);
}

// Round 4
// 666.094 us; speedup vs baseline: 1.2839x; 1.2839x over previous
//
#include <hip/hip_runtime.h>

// ---------------- problem constants ----------------
#define NB    2
#define QLEN  512
#define HIDD  5120
#define QLORA 1536
#define NHEAD 128
#define QHD   192
#define VHD   128
#define KVTOT 1024

typedef float          f32x4   __attribute__((ext_vector_type(4)));
typedef __bf16         bf16x8  __attribute__((ext_vector_type(8)));
typedef unsigned short u16x8   __attribute__((ext_vector_type(8)));
typedef unsigned short u16x4   __attribute__((ext_vector_type(4)));

static __device__ __forceinline__ unsigned short f2bf(float f) {
  union { float f; unsigned u; } v; v.f = f;
  return (unsigned short)((v.u + 0x7fffu + ((v.u >> 16) & 1u)) >> 16);
}

static __device__ __forceinline__ void g2l16(const void* g, void* l) {
  __builtin_amdgcn_global_load_lds(
      (const __attribute__((address_space(1))) void*)g,
      (__attribute__((address_space(3))) void*)l, 16, 0, 0);
}

// ---------------- merged f32 -> bf16 converts (5 segments) ----------------
struct CvtArgs {
  const float* src[5];
  unsigned short* dst[5];
  int off[6];  // cumulative block offsets; each block = 1024 f32x4
};

__global__ __launch_bounds__(256) void cvt_all_k(CvtArgs a) {
  int b = blockIdx.x, s = 0;
  #pragma unroll
  for (int k = 0; k < 4; ++k) if (b >= a.off[k + 1]) s = k + 1;
  long lb = b - a.off[s];
  const float* in = a.src[s];
  unsigned short* out = a.dst[s];
  long base = lb * 1024 + threadIdx.x;
  #pragma unroll
  for (int k = 0; k < 4; ++k) {
    long i = base + k * 256;
    f32x4 v = *(const f32x4*)(in + i * 4);
    u16x4 o;
    o[0] = f2bf(v[0]); o[1] = f2bf(v[1]); o[2] = f2bf(v[2]); o[3] = f2bf(v[3]);
    *(u16x4*)(out + i * 4) = o;
  }
}

// ---------------- mask zero-flags: 1 flag per (b, 128-qtile, 64-ktile) ----------------
__global__ __launch_bounds__(256) void flags_k(const float* __restrict__ mask,
                                               int* __restrict__ flags) {
  int id = blockIdx.x;  // b*64 + qt*16 + kt
  int b = id >> 6, qt = (id >> 4) & 3, kt = id & 15;
  const float* base = mask + (long)b * 524288 + (long)qt * 128 * 1024 + kt * 64;
  int t = threadIdx.x, w = t >> 6;
  unsigned acc = 0;
  #pragma unroll
  for (int i = 0; i < 32; ++i) {
    int e = i * 256 + t;
    int r = e >> 6, c = e & 63;
    union { float f; unsigned u; } v; v.f = base[(long)r * 1024 + c];
    acc |= v.u;
  }
  int any = __any(acc != 0);
  __shared__ int sf[4];
  if ((t & 63) == 0) sf[w] = any;
  __syncthreads();
  if (t == 0) flags[id] = sf[0] | sf[1] | sf[2] | sf[3];
}

// ---------------- fused q_a + ckv GEMM, split-K(4): 128x64 tile, 4 waves ----------------
// B = [w_q_a (1536 rows) ; w_kv_a (576 rows) ; 64 zero rows], rows K-contig.
// writes f32 partials: part[(z*1024 + row)*2176 + col]
__global__ __launch_bounds__(256) void gemm_qa_ckv(const unsigned short* __restrict__ A,
                                                   const unsigned short* __restrict__ Bm,
                                                   float* __restrict__ part) {
  __shared__ __align__(16) unsigned short sA[128 * 64];
  __shared__ __align__(16) unsigned short sB[64 * 64];
  const int t = threadIdx.x, w = t >> 6, l = t & 63;
  const int l15 = l & 15, lh = l >> 4;
  const int mb = blockIdx.y, nb = blockIdx.x, z = blockIdx.z;
  const unsigned short* Ab = A + (long)mb * 128 * HIDD;
  const unsigned short* Bb = Bm + (long)nb * 64 * HIDD;
  f32x4 acc[2][4];
  #pragma unroll
  for (int i = 0; i < 2; ++i)
    #pragma unroll
    for (int j = 0; j < 4; ++j)
      #pragma unroll
      for (int r = 0; r < 4; ++r) acc[i][j][r] = 0.f;

  const int k0 = z * 1280;
  for (int kt = k0; kt < k0 + 1280; kt += 64) {
    #pragma unroll
    for (int i2 = 0; i2 < 4; ++i2) {
      int n = i2 * 256 + t, r = n >> 3, c = n & 7;
      g2l16(Ab + (long)r * HIDD + kt + c * 8, (char*)sA + (i2 * 256 + w * 64) * 16);
    }
    #pragma unroll
    for (int i2 = 0; i2 < 2; ++i2) {
      int n = i2 * 256 + t, r = n >> 3, c = n & 7;
      g2l16(Bb + (long)r * HIDD + kt + c * 8, (char*)sB + (i2 * 256 + w * 64) * 16);
    }
    __syncthreads();
    #pragma unroll
    for (int ks = 0; ks < 2; ++ks) {
      bf16x8 af[2], bfr[4];
      #pragma unroll
      for (int i = 0; i < 2; ++i)
        af[i] = *(const bf16x8*)(sA + (w * 32 + i * 16 + l15) * 64 + ks * 32 + lh * 8);
      #pragma unroll
      for (int j = 0; j < 4; ++j)
        bfr[j] = *(const bf16x8*)(sB + (j * 16 + l15) * 64 + ks * 32 + lh * 8);
      #pragma unroll
      for (int i = 0; i < 2; ++i)
        #pragma unroll
        for (int j = 0; j < 4; ++j)
          acc[i][j] = __builtin_amdgcn_mfma_f32_16x16x32_bf16(af[i], bfr[j], acc[i][j], 0, 0, 0);
    }
    __syncthreads();
  }
  float* po = part + (long)z * 1024 * 2176;
  const int colbase = nb * 64;
  #pragma unroll
  for (int i = 0; i < 2; ++i)
    #pragma unroll
    for (int j = 0; j < 4; ++j) {
      const int col = colbase + j * 16 + l15;
      #pragma unroll
      for (int r4 = 0; r4 < 4; ++r4) {
        const long row = (long)mb * 128 + w * 32 + i * 16 + lh * 4 + r4;
        po[row * 2176 + col] = acc[i][j][r4];
      }
    }
}

// ---------------- fused rmsnorm(q_a) + rmsnorm(ckv) + k_pe broadcast ----------------
__global__ __launch_bounds__(256) void post_a_k(const float* __restrict__ part,
                                                const float* __restrict__ gq,
                                                const float* __restrict__ gkv,
                                                unsigned short* __restrict__ qan,
                                                unsigned short* __restrict__ ckvn,
                                                float* __restrict__ kout,
                                                unsigned short* __restrict__ kb) {
  const long ZS = 1024L * 2176;
  int bid = blockIdx.x, t = threadIdx.x;
  if (bid >= 2048) {  // k_pe broadcast
    int row = bid - 2048;
    int j = t & 63, h0 = t >> 6;
    const float* p = part + (long)row * 2176 + 2048 + j;
    float v = p[0] + p[ZS] + p[2 * ZS] + p[3 * ZS];
    unsigned short vb = f2bf(v);
    long b_ = row >> 9, qi = row & 511;
    for (int h = h0; h < NHEAD; h += 4) {
      long idx = ((b_ * NHEAD + h) * KVTOT + 512 + qi) * QHD + 128 + j;
      kout[idx] = v;
      kb[idx] = vb;
    }
    return;
  }
  bool isQ = bid < 1024;
  int row = isQ ? bid : bid - 1024;
  int cols = isQ ? 1536 : 512;
  const float* g = isQ ? gq : gkv;
  unsigned short* out = isQ ? (qan + (long)row * 1536) : (ckvn + (long)row * 512);
  const float* x = part + (long)row * 2176 + (isQ ? 0 : 1536);
  int w = t >> 6, l = t & 63;
  float xv[6];
  int nc = cols >> 8;
  float ss = 0.f;
  for (int i = 0; i < nc; ++i) {
    int c = t + i * 256;
    float v = x[c] + x[c + ZS] + x[c + 2 * ZS] + x[c + 3 * ZS];
    xv[i] = v; ss += v * v;
  }
  #pragma unroll
  for (int m = 32; m >= 1; m >>= 1) ss += __shfl_xor(ss, m);
  __shared__ float red[4];
  if (l == 0) red[w] = ss;
  __syncthreads();
  float tot = red[0] + red[1] + red[2] + red[3];
  float rs = rsqrtf(tot / (float)cols + 1e-6f);
  for (int i = 0; i < nc; ++i) {
    int c = t + i * 256;
    out[c] = f2bf(g[c] * xv[i] * rs);
  }
}

// ---------------- merged Q-GEMM + KV-GEMM: 128x128 tile, BK=64, 4 waves ----------------
__global__ __launch_bounds__(256) void gemm_bt2(const unsigned short* __restrict__ Aq,
                                                const unsigned short* __restrict__ Bq,
                                                const unsigned short* __restrict__ Akv,
                                                const unsigned short* __restrict__ Bkv,
                                                unsigned short* __restrict__ qout,
                                                float* __restrict__ kout,
                                                float* __restrict__ vout,
                                                unsigned short* __restrict__ kb) {
  __shared__ __align__(16) unsigned short sA[128 * 64];
  __shared__ __align__(16) unsigned short sB[128 * 64];
  const int t = threadIdx.x, w = t >> 6, l = t & 63;
  const int l15 = l & 15, lh = l >> 4;
  const int wm = w >> 1, wn = w & 1;
  const bool isQ = blockIdx.x < 192;
  const int nb = isQ ? blockIdx.x : blockIdx.x - 192;
  const int mb = blockIdx.y;
  const int K = isQ ? QLORA : 512;
  const unsigned short* Ab = (isQ ? Aq : Akv) + (long)mb * 128 * K;
  const unsigned short* Bb = (isQ ? Bq : Bkv) + (long)nb * 128 * K;
  f32x4 acc[4][4];
  #pragma unroll
  for (int i = 0; i < 4; ++i)
    #pragma unroll
    for (int j = 0; j < 4; ++j)
      #pragma unroll
      for (int r = 0; r < 4; ++r) acc[i][j][r] = 0.f;

  const int srow = l >> 3;
  const int scol = (l & 7) * 8;

  for (int kt = 0; kt < K; kt += 64) {
    #pragma unroll
    for (int i = 0; i < 4; ++i) {
      const int chunk = i * 4 + w;
      const int r = chunk * 8 + srow;
      g2l16(Ab + (long)r * K + kt + scol, (char*)sA + chunk * 1024);
      g2l16(Bb + (long)r * K + kt + scol, (char*)sB + chunk * 1024);
    }
    __syncthreads();
    #pragma unroll
    for (int ks = 0; ks < 2; ++ks) {
      bf16x8 af[4], bfr[4];
      #pragma unroll
      for (int i = 0; i < 4; ++i)
        af[i] = *(const bf16x8*)(sA + (wm * 64 + i * 16 + l15) * 64 + ks * 32 + lh * 8);
      #pragma unroll
      for (int j = 0; j < 4; ++j)
        bfr[j] = *(const bf16x8*)(sB + (wn * 64 + j * 16 + l15) * 64 + ks * 32 + lh * 8);
      #pragma unroll
      for (int i = 0; i < 4; ++i)
        #pragma unroll
        for (int j = 0; j < 4; ++j)
          acc[i][j] = __builtin_amdgcn_mfma_f32_16x16x32_bf16(af[i], bfr[j], acc[i][j], 0, 0, 0);
    }
    __syncthreads();
  }

  const long rowbase = (long)mb * 128 + wm * 64;
  const int colbase = nb * 128 + wn * 64;
  #pragma unroll
  for (int i = 0; i < 4; ++i) {
    #pragma unroll
    for (int j = 0; j < 4; ++j) {
      const int col = colbase + j * 16 + l15;
      #pragma unroll
      for (int r4 = 0; r4 < 4; ++r4) {
        const long row = rowbase + i * 16 + lh * 4 + r4;
        const float v = acc[i][j][r4];
        const long b_ = row >> 9, qi = row & 511;
        if (isQ) {
          const int h = col / QHD, d = col - h * QHD;
          qout[(((b_ * NHEAD + h) * QLEN + qi)) * QHD + d] = f2bf(v);
        } else {
          const int h = col >> 8, d = col & 255;
          if (d < 128) {
            const long idx = ((b_ * NHEAD + h) * KVTOT + 512 + qi) * QHD + d;
            kout[idx] = v;
            kb[idx] = f2bf(v);
          } else {
            vout[((b_ * NHEAD + h) * KVTOT + 512 + qi) * VHD + (d - 128)] = v;
          }
        }
      }
    }
  }
}

// ---------------- past key copy: f32 out + bf16 ws ----------------
__global__ __launch_bounds__(256) void copy_key_past_k(const float* __restrict__ pk,
                                                       float* __restrict__ kout,
                                                       unsigned short* __restrict__ kb) {
  long i4 = (long)blockIdx.x * 256 + threadIdx.x;
  f32x4 v = *(const f32x4*)(pk + i4 * 4);
  long e = i4 * 4;
  long bh = e / 98304;
  long rem = e - bh * 98304;
  long oidx = bh * 196608 + rem;
  *(f32x4*)(kout + oidx) = v;
  u16x4 b;
  b[0] = f2bf(v[0]); b[1] = f2bf(v[1]); b[2] = f2bf(v[2]); b[3] = f2bf(v[3]);
  *(u16x4*)(kb + oidx) = b;
}

// ---------------- fused V: past copy (pv->out_val) + full transpose -> Vt bf16 ----------------
__global__ __launch_bounds__(256) void vfix_k(const float* __restrict__ pv,
                                              float* __restrict__ outv,
                                              unsigned short* __restrict__ vt) {
  __shared__ __align__(16) unsigned short sT[128 * 72];
  int bh = blockIdx.x >> 4, kt = blockIdx.x & 15;
  int t = threadIdx.x;
  const float* src = (kt < 8) ? pv + ((long)bh * 512 + kt * 64) * VHD
                              : outv + ((long)bh * KVTOT + kt * 64) * VHD;
  float* dstv = outv + ((long)bh * KVTOT + kt * 64) * VHD;
  #pragma unroll
  for (int i = 0; i < 8; ++i) {
    int id = t + i * 256;
    int r = id >> 5, c4 = (id & 31) * 4;
    f32x4 v = *(const f32x4*)(src + (long)r * VHD + c4);
    if (kt < 8) *(f32x4*)(dstv + (long)r * VHD + c4) = v;
    #pragma unroll
    for (int jj = 0; jj < 4; ++jj) sT[(c4 + jj) * 72 + r] = f2bf(v[jj]);
  }
  __syncthreads();
  #pragma unroll
  for (int i = 0; i < 4; ++i) {
    int id = t + i * 256;
    int d = id >> 3, c = id & 7;
    u16x8 v = *(const u16x8*)(sT + d * 72 + c * 8);
    *(u16x8*)(vt + ((long)bh * VHD + d) * KVTOT + kt * 64 + c * 8) = v;
  }
}

// ---------------- attention staging helpers (XOR-swizzled source, linear LDS dest) ----
static __device__ __forceinline__ void stage_k_tile(const unsigned short* __restrict__ src,
                                                    char* dstbase, int t) {
  const int w = t >> 6;
  #pragma unroll
  for (int i2 = 0; i2 < 6; ++i2) {
    int n = i2 * 256 + t;
    int r = n / 24, cp = n - r * 24;
    int c = cp ^ (r & 7);
    g2l16(src + (long)r * QHD + c * 8, dstbase + (i2 * 256 + w * 64) * 16);
  }
}

static __device__ __forceinline__ void stage_v_tile(const unsigned short* __restrict__ src,
                                                    char* dstbase, int t) {
  const int w = t >> 6;
  #pragma unroll
  for (int i2 = 0; i2 < 4; ++i2) {
    int n = i2 * 256 + t;
    int r = n >> 3, cp = n & 7;
    int c = cp ^ (r & 7);
    g2l16(src + (long)r * KVTOT + c * 8, dstbase + (i2 * 256 + w * 64) * 16);
  }
}

// ---------------- flash attention: 1 block = (b,h, 128-row q tile), 4 waves ----------------
// LDS 64 KB -> 2 blocks/CU. sP aliased into sK[cur]; 2 barriers/iter.
__global__ __launch_bounds__(256, 2) void attn_k(const unsigned short* __restrict__ Qw,
                                                 const unsigned short* __restrict__ Kb,
                                                 const unsigned short* __restrict__ Vt,
                                                 const float* __restrict__ mask,
                                                 const int* __restrict__ flags,
                                                 float* __restrict__ outp) {
  __shared__ __align__(16) unsigned short sK[2][64 * 192];
  __shared__ __align__(16) unsigned short sV[128 * 64];
  const int t = threadIdx.x, w = t >> 6, l = t & 63;
  const int l15 = l & 15, lh = l >> 4;
  // XCD-grouping remap: the 4 q-tiles of one bh land on the same XCD, consecutive slots.
  const int raw = blockIdx.x;
  const int xcd = raw & 7, slot = raw >> 3;
  const int bh = xcd * 32 + (slot >> 2), qt = slot & 3;
  const long b_ = bh >> 7;
  const float SCALE = 0.051023330039633184f;
  const int swz = l15 & 7;

  bf16x8 qf[2][6];
  const unsigned short* Qb = Qw + ((long)bh * QLEN + qt * 128 + w * 32) * QHD;
  #pragma unroll
  for (int i = 0; i < 2; ++i)
    #pragma unroll
    for (int ks = 0; ks < 6; ++ks)
      qf[i][ks] = *(const bf16x8*)(Qb + (i * 16 + l15) * QHD + ks * 32 + lh * 8);

  f32x4 o[2][8];
  #pragma unroll
  for (int i = 0; i < 2; ++i)
    #pragma unroll
    for (int j = 0; j < 8; ++j)
      #pragma unroll
      for (int r = 0; r < 4; ++r) o[i][j][r] = 0.f;
  float m_[2][4], l_[2][4];  // l_ is a per-lane partial (reduced in epilogue)
  #pragma unroll
  for (int i = 0; i < 2; ++i)
    #pragma unroll
    for (int r = 0; r < 4; ++r) { m_[i][r] = -1e30f; l_[i][r] = 0.f; }

  const int qrow0 = qt * 128 + w * 32;
  const unsigned short* Kbh = Kb + (long)bh * KVTOT * QHD;
  const unsigned short* Vbh = Vt + (long)bh * VHD * KVTOT;
  const float* mrow = mask + b_ * 524288 + (long)(qrow0 + lh * 4) * 1024 + l15;
  const int fbase = (int)b_ * 64 + qt * 16;

  // prologue: stage K tile 0
  stage_k_tile(Kbh, (char*)sK[0], t);
  __syncthreads();

  for (int kt = 0; kt < 16; ++kt) {
    const int cur = kt & 1;
    // issue this V tile + next K tile (async; drained at barrier #1)
    stage_v_tile(Vbh + kt * 64, (char*)sV, t);
    if (kt < 15) stage_k_tile(Kbh + (long)(kt + 1) * 64 * QHD, (char*)sK[cur ^ 1], t);
    const int flag = flags[fbase + kt];

    // S = Q K^T  (reads swizzled sK[cur])
    const unsigned short* sKc = sK[cur];
    f32x4 s[2][4];
    #pragma unroll
    for (int i = 0; i < 2; ++i)
      #pragma unroll
      for (int j = 0; j < 4; ++j)
        #pragma unroll
        for (int r = 0; r < 4; ++r) s[i][j][r] = 0.f;
    __builtin_amdgcn_s_setprio(1);
    #pragma unroll
    for (int j = 0; j < 4; ++j) {
      #pragma unroll
      for (int ks = 0; ks < 6; ++ks) {
        bf16x8 kf = *(const bf16x8*)(sKc + ((j * 16 + l15) * 24 + ((ks * 4 + lh) ^ swz)) * 8);
        s[0][j] = __builtin_amdgcn_mfma_f32_16x16x32_bf16(qf[0][ks], kf, s[0][j], 0, 0, 0);
        s[1][j] = __builtin_amdgcn_mfma_f32_16x16x32_bf16(qf[1][ks], kf, s[1][j], 0, 0, 0);
      }
    }
    __builtin_amdgcn_s_setprio(0);

    // online softmax -> p kept in registers; per-lane partial sums (deferred reduce)
    unsigned short pk16[2][4][4];
    #pragma unroll
    for (int i = 0; i < 2; ++i) {
      #pragma unroll
      for (int rg = 0; rg < 4; ++rg) {
        float sc[4];
        if (flag) {
          #pragma unroll
          for (int j = 0; j < 4; ++j)
            sc[j] = s[i][j][rg] * SCALE + mrow[(long)(i * 16 + rg) * 1024 + kt * 64 + j * 16];
        } else {
          #pragma unroll
          for (int j = 0; j < 4; ++j) sc[j] = s[i][j][rg] * SCALE;
        }
        float mx = fmaxf(fmaxf(sc[0], sc[1]), fmaxf(sc[2], sc[3]));
        mx = fmaxf(mx, __shfl_xor(mx, 1));
        mx = fmaxf(mx, __shfl_xor(mx, 2));
        mx = fmaxf(mx, __shfl_xor(mx, 4));
        mx = fmaxf(mx, __shfl_xor(mx, 8));
        float mo = m_[i][rg];
        float mn = fmaxf(mo, mx);
        if (__any(mn > mo)) {
          float al = __expf(mo - mn);
          #pragma unroll
          for (int jj = 0; jj < 8; ++jj) o[i][jj][rg] *= al;
          l_[i][rg] *= al;
          m_[i][rg] = mn;
        }
        float ps = 0.f;
        #pragma unroll
        for (int j = 0; j < 4; ++j) {
          float p = __expf(sc[j] - m_[i][rg]);
          ps += p;
          pk16[i][rg][j] = f2bf(p);
        }
        l_[i][rg] += ps;
      }
    }
    __syncthreads();  // #1: QK^T reads of sK[cur] done; staged V (+next K) drained

    // write P into sP (aliased into sK[cur]); rows are wave-local -> no barrier after
    unsigned short* sPc = (unsigned short*)sK[cur];
    #pragma unroll
    for (int i = 0; i < 2; ++i)
      #pragma unroll
      for (int rg = 0; rg < 4; ++rg) {
        const int prow = w * 32 + i * 16 + lh * 4 + rg;
        #pragma unroll
        for (int j = 0; j < 4; ++j)
          sPc[prow * 72 + j * 16 + l15] = pk16[i][rg][j];
      }

    // O += P V  (P wave-local; V from swizzled sV)
    __builtin_amdgcn_s_setprio(1);
    #pragma unroll
    for (int ks = 0; ks < 2; ++ks) {
      bf16x8 pf0 = *(const bf16x8*)(sPc + (w * 32 + l15) * 72 + ks * 32 + lh * 8);
      bf16x8 pf1 = *(const bf16x8*)(sPc + (w * 32 + 16 + l15) * 72 + ks * 32 + lh * 8);
      #pragma unroll
      for (int jj = 0; jj < 8; ++jj) {
        bf16x8 vf = *(const bf16x8*)(sV + ((jj * 16 + l15) * 8 + ((ks * 4 + lh) ^ swz)) * 8);
        o[0][jj] = __builtin_amdgcn_mfma_f32_16x16x32_bf16(pf0, vf, o[0][jj], 0, 0, 0);
        o[1][jj] = __builtin_amdgcn_mfma_f32_16x16x32_bf16(pf1, vf, o[1][jj], 0, 0, 0);
      }
    }
    __builtin_amdgcn_s_setprio(0);
    __syncthreads();  // #2: PV done before next iter's stages overwrite sK[cur]/sV
  }

  #pragma unroll
  for (int i = 0; i < 2; ++i) {
    #pragma unroll
    for (int rg = 0; rg < 4; ++rg) {
      float ls = l_[i][rg];
      ls += __shfl_xor(ls, 1);
      ls += __shfl_xor(ls, 2);
      ls += __shfl_xor(ls, 4);
      ls += __shfl_xor(ls, 8);
      float inv = 1.0f / ls;
      long row = (long)bh * QLEN + qrow0 + i * 16 + lh * 4 + rg;
      #pragma unroll
      for (int jj = 0; jj < 8; ++jj)
        outp[row * VHD + jj * 16 + l15] = o[i][jj][rg] * inv;
    }
  }
}

// ---------------- workspace layout (bytes) ----------------
#define WS_HID_BF   0L           // 1024x5120 bf16            = 10,485,760
#define WS_WQA_BF   10485760L    // stacked [wqa;wkva;pad] 2176x5120 bf16 = 22,282,240
#define WS_WQB_BF   32768000L    // 24576x1536 bf16           = 75,497,472
#define WS_WKVB_BF  108265472L   // 32768x512 bf16            = 33,554,432
#define WS_QAN_BF   141819904L   // 1024x1536 bf16            =  3,145,728
#define WS_CKVN_BF  144965632L   // 1024x512 bf16             =  1,048,576
#define WS_Q_BF     146014208L   // 50,331,648 (part f32 35.6MB aliased here first)
#define WS_KB_BF    196345856L   // 100,663,296
#define WS_VT_BF    297009152L   // 67,108,864
#define WS_FLAGS    364118016L   // 512
// total ~364.1 MB

extern "C" void kernel_launch(void* const* d_in, const int* in_sizes, int n_in,
                              void* d_out, int out_size, void* d_ws, size_t ws_size,
                              hipStream_t stream) {
  const float* hs   = (const float*)d_in[0];
  const float* mask = (const float*)d_in[1];
  const float* pk   = (const float*)d_in[2];
  const float* pv   = (const float*)d_in[3];
  const float* wqa  = (const float*)d_in[4];
  const float* gqa  = (const float*)d_in[5];
  const float* wqb  = (const float*)d_in[6];
  const float* wkva = (const float*)d_in[7];
  const float* gkva = (const float*)d_in[8];
  const float* wkvb = (const float*)d_in[9];

  char* ws = (char*)d_ws;
  unsigned short* hid_bf  = (unsigned short*)(ws + WS_HID_BF);
  unsigned short* wqa_bf  = (unsigned short*)(ws + WS_WQA_BF);  // stacked [wqa;wkva;pad]
  unsigned short* wkva_bf = wqa_bf + (long)1536 * 5120;
  unsigned short* wqb_bf  = (unsigned short*)(ws + WS_WQB_BF);
  unsigned short* wkvb_bf = (unsigned short*)(ws + WS_WKVB_BF);
  unsigned short* qan_bf  = (unsigned short*)(ws + WS_QAN_BF);
  unsigned short* ckvn_bf = (unsigned short*)(ws + WS_CKVN_BF);
  unsigned short* q_bf    = (unsigned short*)(ws + WS_Q_BF);
  float*          part    = (float*)(ws + WS_Q_BF);  // aliased: dead before q_bf written
  unsigned short* kb_bf   = (unsigned short*)(ws + WS_KB_BF);
  unsigned short* vt_bf   = (unsigned short*)(ws + WS_VT_BF);
  int*            flags   = (int*)(ws + WS_FLAGS);

  float* out_attn = (float*)d_out;
  float* out_key  = (float*)d_out + 16777216;
  float* out_val  = (float*)d_out + 67108864;

  // 0. mask zero-flags
  flags_k<<<128, 256, 0, stream>>>(mask, flags);
  // 1. zero the 64 pad rows of stacked wkva, then all converts in one kernel
  hipMemsetAsync(ws + WS_WQA_BF + (long)2112 * 5120 * 2, 0, (long)64 * 5120 * 2, stream);
  CvtArgs ca;
  ca.src[0] = hs;     ca.dst[0] = hid_bf;
  ca.src[1] = wqa;    ca.dst[1] = wqa_bf;
  ca.src[2] = wkva;   ca.dst[2] = wkva_bf;
  ca.src[3] = wqb;    ca.dst[3] = wqb_bf;
  ca.src[4] = wkvb;   ca.dst[4] = wkvb_bf;
  ca.off[0] = 0; ca.off[1] = 1280; ca.off[2] = 3200; ca.off[3] = 3920;
  ca.off[4] = 13136; ca.off[5] = 17232;
  cvt_all_k<<<17232, 256, 0, stream>>>(ca);
  // 2. past key copy (independent)
  copy_key_past_k<<<24576, 256, 0, stream>>>(pk, out_key, kb_bf);
  // 3. fused q_a + ckv GEMM, split-K(4) -> part
  gemm_qa_ckv<<<dim3(34, 8, 4), 256, 0, stream>>>(hid_bf, wqa_bf, part);
  // 4. fused rmsnorms + k_pe broadcast (sums partials)
  post_a_k<<<3072, 256, 0, stream>>>(part, gqa, gkva, qan_bf, ckvn_bf, out_key, kb_bf);
  // 5. merged Q-GEMM + KV-GEMM (q_bf overwrites part — safe, part is dead)
  gemm_bt2<<<dim3(448, 8), 256, 0, stream>>>(qan_bf, wqb_bf, ckvn_bf, wkvb_bf,
                                             q_bf, out_key, out_val, kb_bf);
  // 6. fused V past-copy + transpose -> Vt bf16
  vfix_k<<<4096, 256, 0, stream>>>(pv, out_val, vt_bf);
  // 7. attention
  attn_k<<<1024, 256, 0, stream>>>(q_bf, kb_bf, vt_bf, mask, flags, out_attn);
}

// Round 5
// 663.171 us; speedup vs baseline: 1.2896x; 1.0044x over previous
//
#include <hip/hip_runtime.h>

// ---------------- problem constants ----------------
#define NB    2
#define QLEN  512
#define HIDD  5120
#define QLORA 1536
#define NHEAD 128
#define QHD   192
#define VHD   128
#define KVTOT 1024

typedef float          f32x4   __attribute__((ext_vector_type(4)));
typedef __bf16         bf16x8  __attribute__((ext_vector_type(8)));
typedef unsigned short u16x8   __attribute__((ext_vector_type(8)));
typedef unsigned short u16x4   __attribute__((ext_vector_type(4)));

static __device__ __forceinline__ unsigned short f2bf(float f) {
  union { float f; unsigned u; } v; v.f = f;
  return (unsigned short)((v.u + 0x7fffu + ((v.u >> 16) & 1u)) >> 16);
}

static __device__ __forceinline__ void g2l16(const void* g, void* l) {
  __builtin_amdgcn_global_load_lds(
      (const __attribute__((address_space(1))) void*)g,
      (__attribute__((address_space(3))) void*)l, 16, 0, 0);
}

// ---------------- merged f32 -> bf16 converts (5 segments) ----------------
struct CvtArgs {
  const float* src[5];
  unsigned short* dst[5];
  int off[6];  // cumulative block offsets; each block = 1024 f32x4
};

__global__ __launch_bounds__(256) void cvt_all_k(CvtArgs a) {
  int b = blockIdx.x, s = 0;
  #pragma unroll
  for (int k = 0; k < 4; ++k) if (b >= a.off[k + 1]) s = k + 1;
  long lb = b - a.off[s];
  const float* in = a.src[s];
  unsigned short* out = a.dst[s];
  long base = lb * 1024 + threadIdx.x;
  #pragma unroll
  for (int k = 0; k < 4; ++k) {
    long i = base + k * 256;
    f32x4 v = *(const f32x4*)(in + i * 4);
    u16x4 o;
    o[0] = f2bf(v[0]); o[1] = f2bf(v[1]); o[2] = f2bf(v[2]); o[3] = f2bf(v[3]);
    *(u16x4*)(out + i * 4) = o;
  }
}

// ---------------- mask zero-flags: 1 flag per (b, 128-qtile, 64-ktile) ----------------
__global__ __launch_bounds__(256) void flags_k(const float* __restrict__ mask,
                                               int* __restrict__ flags) {
  int id = blockIdx.x;  // b*64 + qt*16 + kt
  int b = id >> 6, qt = (id >> 4) & 3, kt = id & 15;
  const float* base = mask + (long)b * 524288 + (long)qt * 128 * 1024 + kt * 64;
  int t = threadIdx.x, w = t >> 6;
  unsigned acc = 0;
  #pragma unroll
  for (int i = 0; i < 32; ++i) {
    int e = i * 256 + t;
    int r = e >> 6, c = e & 63;
    union { float f; unsigned u; } v; v.f = base[(long)r * 1024 + c];
    acc |= v.u;
  }
  int any = __any(acc != 0);
  __shared__ int sf[4];
  if ((t & 63) == 0) sf[w] = any;
  __syncthreads();
  if (t == 0) flags[id] = sf[0] | sf[1] | sf[2] | sf[3];
}

// ---------------- fused q_a + ckv GEMM, split-K(4): 128x64 tile, 4 waves ----------------
// grid (8, 34, 4): x = row-tile (B-panel reuse), y = col-panel, z = split-K
// B = [w_q_a (1536 rows) ; w_kv_a (576 rows) ; 64 zero rows], rows K-contig.
// writes f32 partials: part[(z*1024 + row)*2176 + col]
__global__ __launch_bounds__(256) void gemm_qa_ckv(const unsigned short* __restrict__ A,
                                                   const unsigned short* __restrict__ Bm,
                                                   float* __restrict__ part) {
  __shared__ __align__(16) unsigned short sA[128 * 64];
  __shared__ __align__(16) unsigned short sB[64 * 64];
  const int t = threadIdx.x, w = t >> 6, l = t & 63;
  const int l15 = l & 15, lh = l >> 4;
  const int swz7 = l15 & 7;
  const int mb = blockIdx.x, nb = blockIdx.y, z = blockIdx.z;
  const unsigned short* Ab = A + (long)mb * 128 * HIDD;
  const unsigned short* Bb = Bm + (long)nb * 64 * HIDD;
  f32x4 acc[2][4];
  #pragma unroll
  for (int i = 0; i < 2; ++i)
    #pragma unroll
    for (int j = 0; j < 4; ++j)
      #pragma unroll
      for (int r = 0; r < 4; ++r) acc[i][j][r] = 0.f;

  const int k0 = z * 1280;
  for (int kt = k0; kt < k0 + 1280; kt += 64) {
    #pragma unroll
    for (int i2 = 0; i2 < 4; ++i2) {
      int n = i2 * 256 + t, r = n >> 3, c = (n & 7) ^ (r & 7);
      g2l16(Ab + (long)r * HIDD + kt + c * 8, (char*)sA + (i2 * 256 + w * 64) * 16);
    }
    #pragma unroll
    for (int i2 = 0; i2 < 2; ++i2) {
      int n = i2 * 256 + t, r = n >> 3, c = (n & 7) ^ (r & 7);
      g2l16(Bb + (long)r * HIDD + kt + c * 8, (char*)sB + (i2 * 256 + w * 64) * 16);
    }
    __syncthreads();
    #pragma unroll
    for (int ks = 0; ks < 2; ++ks) {
      bf16x8 af[2], bfr[4];
      #pragma unroll
      for (int i = 0; i < 2; ++i)
        af[i] = *(const bf16x8*)(sA + (w * 32 + i * 16 + l15) * 64 + ((ks * 4 + lh) ^ swz7) * 8);
      #pragma unroll
      for (int j = 0; j < 4; ++j)
        bfr[j] = *(const bf16x8*)(sB + (j * 16 + l15) * 64 + ((ks * 4 + lh) ^ swz7) * 8);
      #pragma unroll
      for (int i = 0; i < 2; ++i)
        #pragma unroll
        for (int j = 0; j < 4; ++j)
          acc[i][j] = __builtin_amdgcn_mfma_f32_16x16x32_bf16(af[i], bfr[j], acc[i][j], 0, 0, 0);
    }
    __syncthreads();
  }
  float* po = part + (long)z * 1024 * 2176;
  const int colbase = nb * 64;
  #pragma unroll
  for (int i = 0; i < 2; ++i)
    #pragma unroll
    for (int j = 0; j < 4; ++j) {
      const int col = colbase + j * 16 + l15;
      #pragma unroll
      for (int r4 = 0; r4 < 4; ++r4) {
        const long row = (long)mb * 128 + w * 32 + i * 16 + lh * 4 + r4;
        po[row * 2176 + col] = acc[i][j][r4];
      }
    }
}

// ---------------- fused rmsnorm(q_a) + rmsnorm(ckv) + k_pe broadcast ----------------
__global__ __launch_bounds__(256) void post_a_k(const float* __restrict__ part,
                                                const float* __restrict__ gq,
                                                const float* __restrict__ gkv,
                                                unsigned short* __restrict__ qan,
                                                unsigned short* __restrict__ ckvn,
                                                float* __restrict__ kout,
                                                unsigned short* __restrict__ kb) {
  const long ZS = 1024L * 2176;
  int bid = blockIdx.x, t = threadIdx.x;
  if (bid >= 2048) {  // k_pe broadcast
    int row = bid - 2048;
    int j = t & 63, h0 = t >> 6;
    const float* p = part + (long)row * 2176 + 2048 + j;
    float v = p[0] + p[ZS] + p[2 * ZS] + p[3 * ZS];
    unsigned short vb = f2bf(v);
    long b_ = row >> 9, qi = row & 511;
    for (int h = h0; h < NHEAD; h += 4) {
      long idx = ((b_ * NHEAD + h) * KVTOT + 512 + qi) * QHD + 128 + j;
      kout[idx] = v;
      kb[idx] = vb;
    }
    return;
  }
  bool isQ = bid < 1024;
  int row = isQ ? bid : bid - 1024;
  int cols = isQ ? 1536 : 512;
  const float* g = isQ ? gq : gkv;
  unsigned short* out = isQ ? (qan + (long)row * 1536) : (ckvn + (long)row * 512);
  const float* x = part + (long)row * 2176 + (isQ ? 0 : 1536);
  int w = t >> 6, l = t & 63;
  float xv[6];
  int nc = cols >> 8;
  float ss = 0.f;
  for (int i = 0; i < nc; ++i) {
    int c = t + i * 256;
    float v = x[c] + x[c + ZS] + x[c + 2 * ZS] + x[c + 3 * ZS];
    xv[i] = v; ss += v * v;
  }
  #pragma unroll
  for (int m = 32; m >= 1; m >>= 1) ss += __shfl_xor(ss, m);
  __shared__ float red[4];
  if (l == 0) red[w] = ss;
  __syncthreads();
  float tot = red[0] + red[1] + red[2] + red[3];
  float rs = rsqrtf(tot / (float)cols + 1e-6f);
  for (int i = 0; i < nc; ++i) {
    int c = t + i * 256;
    out[c] = f2bf(g[c] * xv[i] * rs);
  }
}

// ---------------- merged Q-GEMM + KV-GEMM: 128x128 tile, BK=64, 4 waves ----------------
// grid (8, 448): x = row-tile (inner, B-panel reuse across XCDs), y = col-panel.
// y < 192: Q GEMM (A=qan,B=wqb,K=1536); y >= 192: KV GEMM (A=ckvn,B=wkvb,K=512)
__global__ __launch_bounds__(256) void gemm_bt2(const unsigned short* __restrict__ Aq,
                                                const unsigned short* __restrict__ Bq,
                                                const unsigned short* __restrict__ Akv,
                                                const unsigned short* __restrict__ Bkv,
                                                unsigned short* __restrict__ qout,
                                                float* __restrict__ kout,
                                                float* __restrict__ vout,
                                                unsigned short* __restrict__ kb) {
  __shared__ __align__(16) unsigned short sA[128 * 64];
  __shared__ __align__(16) unsigned short sB[128 * 64];
  const int t = threadIdx.x, w = t >> 6, l = t & 63;
  const int l15 = l & 15, lh = l >> 4;
  const int swz7 = l15 & 7;
  const int wm = w >> 1, wn = w & 1;
  const bool isQ = blockIdx.y < 192;
  const int nb = isQ ? blockIdx.y : blockIdx.y - 192;
  const int mb = blockIdx.x;
  const int K = isQ ? QLORA : 512;
  const unsigned short* Ab = (isQ ? Aq : Akv) + (long)mb * 128 * K;
  const unsigned short* Bb = (isQ ? Bq : Bkv) + (long)nb * 128 * K;
  f32x4 acc[4][4];
  #pragma unroll
  for (int i = 0; i < 4; ++i)
    #pragma unroll
    for (int j = 0; j < 4; ++j)
      #pragma unroll
      for (int r = 0; r < 4; ++r) acc[i][j][r] = 0.f;

  const int srow = l >> 3;
  const int scol = ((l & 7) ^ srow) * 8;  // XOR-swizzled source chunk

  for (int kt = 0; kt < K; kt += 64) {
    #pragma unroll
    for (int i = 0; i < 4; ++i) {
      const int chunk = i * 4 + w;
      const int r = chunk * 8 + srow;
      g2l16(Ab + (long)r * K + kt + scol, (char*)sA + chunk * 1024);
      g2l16(Bb + (long)r * K + kt + scol, (char*)sB + chunk * 1024);
    }
    __syncthreads();
    #pragma unroll
    for (int ks = 0; ks < 2; ++ks) {
      bf16x8 af[4], bfr[4];
      #pragma unroll
      for (int i = 0; i < 4; ++i)
        af[i] = *(const bf16x8*)(sA + (wm * 64 + i * 16 + l15) * 64 + ((ks * 4 + lh) ^ swz7) * 8);
      #pragma unroll
      for (int j = 0; j < 4; ++j)
        bfr[j] = *(const bf16x8*)(sB + (wn * 64 + j * 16 + l15) * 64 + ((ks * 4 + lh) ^ swz7) * 8);
      #pragma unroll
      for (int i = 0; i < 4; ++i)
        #pragma unroll
        for (int j = 0; j < 4; ++j)
          acc[i][j] = __builtin_amdgcn_mfma_f32_16x16x32_bf16(af[i], bfr[j], acc[i][j], 0, 0, 0);
    }
    __syncthreads();
  }

  const long rowbase = (long)mb * 128 + wm * 64;
  const int colbase = nb * 128 + wn * 64;
  #pragma unroll
  for (int i = 0; i < 4; ++i) {
    #pragma unroll
    for (int j = 0; j < 4; ++j) {
      const int col = colbase + j * 16 + l15;
      #pragma unroll
      for (int r4 = 0; r4 < 4; ++r4) {
        const long row = rowbase + i * 16 + lh * 4 + r4;
        const float v = acc[i][j][r4];
        const long b_ = row >> 9, qi = row & 511;
        if (isQ) {
          const int h = col / QHD, d = col - h * QHD;
          qout[(((b_ * NHEAD + h) * QLEN + qi)) * QHD + d] = f2bf(v);
        } else {
          const int h = col >> 8, d = col & 255;
          if (d < 128) {
            const long idx = ((b_ * NHEAD + h) * KVTOT + 512 + qi) * QHD + d;
            kout[idx] = v;
            kb[idx] = f2bf(v);
          } else {
            vout[((b_ * NHEAD + h) * KVTOT + 512 + qi) * VHD + (d - 128)] = v;
          }
        }
      }
    }
  }
}

// ---------------- past key copy: f32 out + bf16 ws ----------------
__global__ __launch_bounds__(256) void copy_key_past_k(const float* __restrict__ pk,
                                                       float* __restrict__ kout,
                                                       unsigned short* __restrict__ kb) {
  long i4 = (long)blockIdx.x * 256 + threadIdx.x;
  f32x4 v = *(const f32x4*)(pk + i4 * 4);
  long e = i4 * 4;
  long bh = e / 98304;
  long rem = e - bh * 98304;
  long oidx = bh * 196608 + rem;
  *(f32x4*)(kout + oidx) = v;
  u16x4 b;
  b[0] = f2bf(v[0]); b[1] = f2bf(v[1]); b[2] = f2bf(v[2]); b[3] = f2bf(v[3]);
  *(u16x4*)(kb + oidx) = b;
}

// ---------------- fused V: past copy (pv->out_val) + full transpose -> Vt bf16 ----------------
__global__ __launch_bounds__(256) void vfix_k(const float* __restrict__ pv,
                                              float* __restrict__ outv,
                                              unsigned short* __restrict__ vt) {
  __shared__ __align__(16) unsigned short sT[128 * 72];
  int bh = blockIdx.x >> 4, kt = blockIdx.x & 15;
  int t = threadIdx.x;
  const float* src = (kt < 8) ? pv + ((long)bh * 512 + kt * 64) * VHD
                              : outv + ((long)bh * KVTOT + kt * 64) * VHD;
  float* dstv = outv + ((long)bh * KVTOT + kt * 64) * VHD;
  #pragma unroll
  for (int i = 0; i < 8; ++i) {
    int id = t + i * 256;
    int r = id >> 5, c4 = (id & 31) * 4;
    f32x4 v = *(const f32x4*)(src + (long)r * VHD + c4);
    if (kt < 8) *(f32x4*)(dstv + (long)r * VHD + c4) = v;
    #pragma unroll
    for (int jj = 0; jj < 4; ++jj) sT[(c4 + jj) * 72 + r] = f2bf(v[jj]);
  }
  __syncthreads();
  #pragma unroll
  for (int i = 0; i < 4; ++i) {
    int id = t + i * 256;
    int d = id >> 3, c = id & 7;
    u16x8 v = *(const u16x8*)(sT + d * 72 + c * 8);
    *(u16x8*)(vt + ((long)bh * VHD + d) * KVTOT + kt * 64 + c * 8) = v;
  }
}

// ---------------- attention staging helpers (XOR-swizzled source, linear LDS dest) ----
static __device__ __forceinline__ void stage_k_tile(const unsigned short* __restrict__ src,
                                                    char* dstbase, int t) {
  const int w = t >> 6;
  #pragma unroll
  for (int i2 = 0; i2 < 6; ++i2) {
    int n = i2 * 256 + t;
    int r = n / 24, cp = n - r * 24;
    int c = cp ^ (r & 7);
    g2l16(src + (long)r * QHD + c * 8, dstbase + (i2 * 256 + w * 64) * 16);
  }
}

static __device__ __forceinline__ void stage_v_tile(const unsigned short* __restrict__ src,
                                                    char* dstbase, int t) {
  const int w = t >> 6;
  #pragma unroll
  for (int i2 = 0; i2 < 4; ++i2) {
    int n = i2 * 256 + t;
    int r = n >> 3, cp = n & 7;
    int c = cp ^ (r & 7);
    g2l16(src + (long)r * KVTOT + c * 8, dstbase + (i2 * 256 + w * 64) * 16);
  }
}

// ---------------- flash attention: 1 block = (b,h, 128-row q tile), 4 waves ----------------
// LDS 64 KB -> 2 blocks/CU. sP aliased into sK[cur]; 2 barriers/iter.
__global__ __launch_bounds__(256, 2) void attn_k(const unsigned short* __restrict__ Qw,
                                                 const unsigned short* __restrict__ Kb,
                                                 const unsigned short* __restrict__ Vt,
                                                 const float* __restrict__ mask,
                                                 const int* __restrict__ flags,
                                                 float* __restrict__ outp) {
  __shared__ __align__(16) unsigned short sK[2][64 * 192];
  __shared__ __align__(16) unsigned short sV[128 * 64];
  const int t = threadIdx.x, w = t >> 6, l = t & 63;
  const int l15 = l & 15, lh = l >> 4;
  const int raw = blockIdx.x;
  const int xcd = raw & 7, slot = raw >> 3;
  const int bh = xcd * 32 + (slot >> 2), qt = slot & 3;
  const long b_ = bh >> 7;
  const float SCALE = 0.051023330039633184f;
  const int swz = l15 & 7;

  bf16x8 qf[2][6];
  const unsigned short* Qb = Qw + ((long)bh * QLEN + qt * 128 + w * 32) * QHD;
  #pragma unroll
  for (int i = 0; i < 2; ++i)
    #pragma unroll
    for (int ks = 0; ks < 6; ++ks)
      qf[i][ks] = *(const bf16x8*)(Qb + (i * 16 + l15) * QHD + ks * 32 + lh * 8);

  f32x4 o[2][8];
  #pragma unroll
  for (int i = 0; i < 2; ++i)
    #pragma unroll
    for (int j = 0; j < 8; ++j)
      #pragma unroll
      for (int r = 0; r < 4; ++r) o[i][j][r] = 0.f;
  float m_[2][4], l_[2][4];  // l_ is a per-lane partial (reduced in epilogue)
  #pragma unroll
  for (int i = 0; i < 2; ++i)
    #pragma unroll
    for (int r = 0; r < 4; ++r) { m_[i][r] = -1e30f; l_[i][r] = 0.f; }

  const int qrow0 = qt * 128 + w * 32;
  const unsigned short* Kbh = Kb + (long)bh * KVTOT * QHD;
  const unsigned short* Vbh = Vt + (long)bh * VHD * KVTOT;
  const float* mrow = mask + b_ * 524288 + (long)(qrow0 + lh * 4) * 1024 + l15;
  const int fbase = (int)b_ * 64 + qt * 16;

  stage_k_tile(Kbh, (char*)sK[0], t);
  __syncthreads();

  for (int kt = 0; kt < 16; ++kt) {
    const int cur = kt & 1;
    stage_v_tile(Vbh + kt * 64, (char*)sV, t);
    if (kt < 15) stage_k_tile(Kbh + (long)(kt + 1) * 64 * QHD, (char*)sK[cur ^ 1], t);
    const int flag = flags[fbase + kt];

    const unsigned short* sKc = sK[cur];
    f32x4 s[2][4];
    #pragma unroll
    for (int i = 0; i < 2; ++i)
      #pragma unroll
      for (int j = 0; j < 4; ++j)
        #pragma unroll
        for (int r = 0; r < 4; ++r) s[i][j][r] = 0.f;
    __builtin_amdgcn_s_setprio(1);
    #pragma unroll
    for (int j = 0; j < 4; ++j) {
      #pragma unroll
      for (int ks = 0; ks < 6; ++ks) {
        bf16x8 kf = *(const bf16x8*)(sKc + ((j * 16 + l15) * 24 + ((ks * 4 + lh) ^ swz)) * 8);
        s[0][j] = __builtin_amdgcn_mfma_f32_16x16x32_bf16(qf[0][ks], kf, s[0][j], 0, 0, 0);
        s[1][j] = __builtin_amdgcn_mfma_f32_16x16x32_bf16(qf[1][ks], kf, s[1][j], 0, 0, 0);
      }
    }
    __builtin_amdgcn_s_setprio(0);

    unsigned short pk16[2][4][4];
    #pragma unroll
    for (int i = 0; i < 2; ++i) {
      #pragma unroll
      for (int rg = 0; rg < 4; ++rg) {
        float sc[4];
        if (flag) {
          #pragma unroll
          for (int j = 0; j < 4; ++j)
            sc[j] = s[i][j][rg] * SCALE + mrow[(long)(i * 16 + rg) * 1024 + kt * 64 + j * 16];
        } else {
          #pragma unroll
          for (int j = 0; j < 4; ++j) sc[j] = s[i][j][rg] * SCALE;
        }
        float mx = fmaxf(fmaxf(sc[0], sc[1]), fmaxf(sc[2], sc[3]));
        mx = fmaxf(mx, __shfl_xor(mx, 1));
        mx = fmaxf(mx, __shfl_xor(mx, 2));
        mx = fmaxf(mx, __shfl_xor(mx, 4));
        mx = fmaxf(mx, __shfl_xor(mx, 8));
        float mo = m_[i][rg];
        float mn = fmaxf(mo, mx);
        if (__any(mn > mo)) {
          float al = __expf(mo - mn);
          #pragma unroll
          for (int jj = 0; jj < 8; ++jj) o[i][jj][rg] *= al;
          l_[i][rg] *= al;
          m_[i][rg] = mn;
        }
        float ps = 0.f;
        #pragma unroll
        for (int j = 0; j < 4; ++j) {
          float p = __expf(sc[j] - m_[i][rg]);
          ps += p;
          pk16[i][rg][j] = f2bf(p);
        }
        l_[i][rg] += ps;
      }
    }
    __syncthreads();  // #1: QK^T reads of sK[cur] done; staged V (+next K) drained

    unsigned short* sPc = (unsigned short*)sK[cur];
    #pragma unroll
    for (int i = 0; i < 2; ++i)
      #pragma unroll
      for (int rg = 0; rg < 4; ++rg) {
        const int prow = w * 32 + i * 16 + lh * 4 + rg;
        #pragma unroll
        for (int j = 0; j < 4; ++j)
          sPc[prow * 72 + j * 16 + l15] = pk16[i][rg][j];
      }

    __builtin_amdgcn_s_setprio(1);
    #pragma unroll
    for (int ks = 0; ks < 2; ++ks) {
      bf16x8 pf0 = *(const bf16x8*)(sPc + (w * 32 + l15) * 72 + ks * 32 + lh * 8);
      bf16x8 pf1 = *(const bf16x8*)(sPc + (w * 32 + 16 + l15) * 72 + ks * 32 + lh * 8);
      #pragma unroll
      for (int jj = 0; jj < 8; ++jj) {
        bf16x8 vf = *(const bf16x8*)(sV + ((jj * 16 + l15) * 8 + ((ks * 4 + lh) ^ swz)) * 8);
        o[0][jj] = __builtin_amdgcn_mfma_f32_16x16x32_bf16(pf0, vf, o[0][jj], 0, 0, 0);
        o[1][jj] = __builtin_amdgcn_mfma_f32_16x16x32_bf16(pf1, vf, o[1][jj], 0, 0, 0);
      }
    }
    __builtin_amdgcn_s_setprio(0);
    __syncthreads();  // #2: PV done before next iter's stages overwrite sK[cur]/sV
  }

  #pragma unroll
  for (int i = 0; i < 2; ++i) {
    #pragma unroll
    for (int rg = 0; rg < 4; ++rg) {
      float ls = l_[i][rg];
      ls += __shfl_xor(ls, 1);
      ls += __shfl_xor(ls, 2);
      ls += __shfl_xor(ls, 4);
      ls += __shfl_xor(ls, 8);
      float inv = 1.0f / ls;
      long row = (long)bh * QLEN + qrow0 + i * 16 + lh * 4 + rg;
      #pragma unroll
      for (int jj = 0; jj < 8; ++jj)
        outp[row * VHD + jj * 16 + l15] = o[i][jj][rg] * inv;
    }
  }
}

// ---------------- workspace layout (bytes) ----------------
#define WS_HID_BF   0L           // 1024x5120 bf16            = 10,485,760
#define WS_WQA_BF   10485760L    // stacked [wqa;wkva;pad] 2176x5120 bf16 = 22,282,240
#define WS_WQB_BF   32768000L    // 24576x1536 bf16           = 75,497,472
#define WS_WKVB_BF  108265472L   // 32768x512 bf16            = 33,554,432
#define WS_QAN_BF   141819904L   // 1024x1536 bf16            =  3,145,728
#define WS_CKVN_BF  144965632L   // 1024x512 bf16             =  1,048,576
#define WS_Q_BF     146014208L   // 50,331,648 (part f32 35.6MB aliased here first)
#define WS_KB_BF    196345856L   // 100,663,296
#define WS_VT_BF    297009152L   // 67,108,864
#define WS_FLAGS    364118016L   // 512
// total ~364.1 MB

extern "C" void kernel_launch(void* const* d_in, const int* in_sizes, int n_in,
                              void* d_out, int out_size, void* d_ws, size_t ws_size,
                              hipStream_t stream) {
  const float* hs   = (const float*)d_in[0];
  const float* mask = (const float*)d_in[1];
  const float* pk   = (const float*)d_in[2];
  const float* pv   = (const float*)d_in[3];
  const float* wqa  = (const float*)d_in[4];
  const float* gqa  = (const float*)d_in[5];
  const float* wqb  = (const float*)d_in[6];
  const float* wkva = (const float*)d_in[7];
  const float* gkva = (const float*)d_in[8];
  const float* wkvb = (const float*)d_in[9];

  char* ws = (char*)d_ws;
  unsigned short* hid_bf  = (unsigned short*)(ws + WS_HID_BF);
  unsigned short* wqa_bf  = (unsigned short*)(ws + WS_WQA_BF);  // stacked [wqa;wkva;pad]
  unsigned short* wkva_bf = wqa_bf + (long)1536 * 5120;
  unsigned short* wqb_bf  = (unsigned short*)(ws + WS_WQB_BF);
  unsigned short* wkvb_bf = (unsigned short*)(ws + WS_WKVB_BF);
  unsigned short* qan_bf  = (unsigned short*)(ws + WS_QAN_BF);
  unsigned short* ckvn_bf = (unsigned short*)(ws + WS_CKVN_BF);
  unsigned short* q_bf    = (unsigned short*)(ws + WS_Q_BF);
  float*          part    = (float*)(ws + WS_Q_BF);  // aliased: dead before q_bf written
  unsigned short* kb_bf   = (unsigned short*)(ws + WS_KB_BF);
  unsigned short* vt_bf   = (unsigned short*)(ws + WS_VT_BF);
  int*            flags   = (int*)(ws + WS_FLAGS);

  float* out_attn = (float*)d_out;
  float* out_key  = (float*)d_out + 16777216;
  float* out_val  = (float*)d_out + 67108864;

  // 0. mask zero-flags
  flags_k<<<128, 256, 0, stream>>>(mask, flags);
  // 1. zero the 64 pad rows of stacked wkva, then all converts in one kernel
  hipMemsetAsync(ws + WS_WQA_BF + (long)2112 * 5120 * 2, 0, (long)64 * 5120 * 2, stream);
  CvtArgs ca;
  ca.src[0] = hs;     ca.dst[0] = hid_bf;
  ca.src[1] = wqa;    ca.dst[1] = wqa_bf;
  ca.src[2] = wkva;   ca.dst[2] = wkva_bf;
  ca.src[3] = wqb;    ca.dst[3] = wqb_bf;
  ca.src[4] = wkvb;   ca.dst[4] = wkvb_bf;
  ca.off[0] = 0; ca.off[1] = 1280; ca.off[2] = 3200; ca.off[3] = 3920;
  ca.off[4] = 13136; ca.off[5] = 17232;
  cvt_all_k<<<17232, 256, 0, stream>>>(ca);
  // 2. past key copy (independent)
  copy_key_past_k<<<24576, 256, 0, stream>>>(pk, out_key, kb_bf);
  // 3. fused q_a + ckv GEMM, split-K(4) -> part  (x = row-tile for B reuse)
  gemm_qa_ckv<<<dim3(8, 34, 4), 256, 0, stream>>>(hid_bf, wqa_bf, part);
  // 4. fused rmsnorms + k_pe broadcast (sums partials)
  post_a_k<<<3072, 256, 0, stream>>>(part, gqa, gkva, qan_bf, ckvn_bf, out_key, kb_bf);
  // 5. merged Q-GEMM + KV-GEMM (x = row-tile for B-panel reuse)
  gemm_bt2<<<dim3(8, 448), 256, 0, stream>>>(qan_bf, wqb_bf, ckvn_bf, wkvb_bf,
                                             q_bf, out_key, out_val, kb_bf);
  // 6. fused V past-copy + transpose -> Vt bf16
  vfix_k<<<4096, 256, 0, stream>>>(pv, out_val, vt_bf);
  // 7. attention
  attn_k<<<1024, 256, 0, stream>>>(q_bf, kb_bf, vt_bf, mask, flags, out_attn);
}

// Round 6
// 578.540 us; speedup vs baseline: 1.4782x; 1.1463x over previous
//
#include <hip/hip_runtime.h>

// ---------------- problem constants ----------------
#define NB    2
#define QLEN  512
#define HIDD  5120
#define QLORA 1536
#define NHEAD 128
#define QHD   192
#define VHD   128
#define KVTOT 1024

typedef float          f32x4   __attribute__((ext_vector_type(4)));
typedef __bf16         bf16x8  __attribute__((ext_vector_type(8)));
typedef unsigned short u16x8   __attribute__((ext_vector_type(8)));
typedef unsigned short u16x4   __attribute__((ext_vector_type(4)));

static __device__ __forceinline__ unsigned short f2bf(float f) {
  union { float f; unsigned u; } v; v.f = f;
  return (unsigned short)((v.u + 0x7fffu + ((v.u >> 16) & 1u)) >> 16);
}

static __device__ __forceinline__ void g2l16(const void* g, void* l) {
  __builtin_amdgcn_global_load_lds(
      (const __attribute__((address_space(1))) void*)g,
      (__attribute__((address_space(3))) void*)l, 16, 0, 0);
}

// ---------------- merged f32 -> bf16 converts (5 segments) ----------------
struct CvtArgs {
  const float* src[5];
  unsigned short* dst[5];
  int off[6];  // cumulative block offsets; each block = 1024 f32x4
};

__global__ __launch_bounds__(256) void cvt_all_k(CvtArgs a) {
  int b = blockIdx.x, s = 0;
  #pragma unroll
  for (int k = 0; k < 4; ++k) if (b >= a.off[k + 1]) s = k + 1;
  long lb = b - a.off[s];
  const float* in = a.src[s];
  unsigned short* out = a.dst[s];
  long base = lb * 1024 + threadIdx.x;
  #pragma unroll
  for (int k = 0; k < 4; ++k) {
    long i = base + k * 256;
    f32x4 v = *(const f32x4*)(in + i * 4);
    u16x4 o;
    o[0] = f2bf(v[0]); o[1] = f2bf(v[1]); o[2] = f2bf(v[2]); o[3] = f2bf(v[3]);
    *(u16x4*)(out + i * 4) = o;
  }
}

// ---------------- mask zero-flags: 1 flag per (b, 128-qtile, 64-ktile) ----------------
__global__ __launch_bounds__(256) void flags_k(const float* __restrict__ mask,
                                               int* __restrict__ flags) {
  int id = blockIdx.x;  // b*64 + qt*16 + kt
  int b = id >> 6, qt = (id >> 4) & 3, kt = id & 15;
  const float* base = mask + (long)b * 524288 + (long)qt * 128 * 1024 + kt * 64;
  int t = threadIdx.x, w = t >> 6;
  unsigned acc = 0;
  #pragma unroll
  for (int i = 0; i < 32; ++i) {
    int e = i * 256 + t;
    int r = e >> 6, c = e & 63;
    union { float f; unsigned u; } v; v.f = base[(long)r * 1024 + c];
    acc |= v.u;
  }
  int any = __any(acc != 0);
  __shared__ int sf[4];
  if ((t & 63) == 0) sf[w] = any;
  __syncthreads();
  if (t == 0) flags[id] = sf[0] | sf[1] | sf[2] | sf[3];
}

// ---------------- fused q_a + ckv GEMM, split-K(4): 128x64 tile, 4 waves ----------------
// 1D grid 1088, XCD-correct remap: all 8 row-tiles of a (panel,z) on ONE XCD.
// B = [w_q_a (1536 rows) ; w_kv_a (576 rows) ; 64 zero rows], rows K-contig.
// writes f32 partials: part[(z*1024 + row)*2176 + col]
__global__ __launch_bounds__(256, 4) void gemm_qa_ckv(const unsigned short* __restrict__ A,
                                                      const unsigned short* __restrict__ Bm,
                                                      float* __restrict__ part) {
  __shared__ __align__(16) unsigned short sA[128 * 64];
  __shared__ __align__(16) unsigned short sB[64 * 64];
  const int t = threadIdx.x, w = t >> 6, l = t & 63;
  const int l15 = l & 15, lh = l >> 4;
  const int swz7 = l15 & 7;
  // remap: xcd = id%8; panel-z index pz = xcd + 8*(slot/8) in [0,136); row-tile = slot%8
  const int id = blockIdx.x;
  const int xcd = id & 7, slot = id >> 3;
  const int pz = xcd + 8 * (slot >> 3);
  const int mb = slot & 7;
  const int z = pz / 34;
  const int nb = pz - z * 34;
  const unsigned short* Ab = A + (long)mb * 128 * HIDD;
  const unsigned short* Bb = Bm + (long)nb * 64 * HIDD;
  f32x4 acc[2][4];
  #pragma unroll
  for (int i = 0; i < 2; ++i)
    #pragma unroll
    for (int j = 0; j < 4; ++j)
      #pragma unroll
      for (int r = 0; r < 4; ++r) acc[i][j][r] = 0.f;

  const int k0 = z * 1280;
  for (int kt = k0; kt < k0 + 1280; kt += 64) {
    #pragma unroll
    for (int i2 = 0; i2 < 4; ++i2) {
      int n = i2 * 256 + t, r = n >> 3, c = (n & 7) ^ (r & 7);
      g2l16(Ab + (long)r * HIDD + kt + c * 8, (char*)sA + (i2 * 256 + w * 64) * 16);
    }
    #pragma unroll
    for (int i2 = 0; i2 < 2; ++i2) {
      int n = i2 * 256 + t, r = n >> 3, c = (n & 7) ^ (r & 7);
      g2l16(Bb + (long)r * HIDD + kt + c * 8, (char*)sB + (i2 * 256 + w * 64) * 16);
    }
    __syncthreads();
    #pragma unroll
    for (int ks = 0; ks < 2; ++ks) {
      bf16x8 af[2], bfr[4];
      #pragma unroll
      for (int i = 0; i < 2; ++i)
        af[i] = *(const bf16x8*)(sA + (w * 32 + i * 16 + l15) * 64 + ((ks * 4 + lh) ^ swz7) * 8);
      #pragma unroll
      for (int j = 0; j < 4; ++j)
        bfr[j] = *(const bf16x8*)(sB + (j * 16 + l15) * 64 + ((ks * 4 + lh) ^ swz7) * 8);
      #pragma unroll
      for (int i = 0; i < 2; ++i)
        #pragma unroll
        for (int j = 0; j < 4; ++j)
          acc[i][j] = __builtin_amdgcn_mfma_f32_16x16x32_bf16(af[i], bfr[j], acc[i][j], 0, 0, 0);
    }
    __syncthreads();
  }
  float* po = part + (long)z * 1024 * 2176;
  const int colbase = nb * 64;
  #pragma unroll
  for (int i = 0; i < 2; ++i)
    #pragma unroll
    for (int j = 0; j < 4; ++j) {
      const int col = colbase + j * 16 + l15;
      #pragma unroll
      for (int r4 = 0; r4 < 4; ++r4) {
        const long row = (long)mb * 128 + w * 32 + i * 16 + lh * 4 + r4;
        po[row * 2176 + col] = acc[i][j][r4];
      }
    }
}

// ---------------- fused rmsnorm(q_a) + rmsnorm(ckv) + k_pe broadcast ----------------
__global__ __launch_bounds__(256) void post_a_k(const float* __restrict__ part,
                                                const float* __restrict__ gq,
                                                const float* __restrict__ gkv,
                                                unsigned short* __restrict__ qan,
                                                unsigned short* __restrict__ ckvn,
                                                float* __restrict__ kout,
                                                unsigned short* __restrict__ kb) {
  const long ZS = 1024L * 2176;
  int bid = blockIdx.x, t = threadIdx.x;
  if (bid >= 2048) {  // k_pe broadcast
    int row = bid - 2048;
    int j = t & 63, h0 = t >> 6;
    const float* p = part + (long)row * 2176 + 2048 + j;
    float v = p[0] + p[ZS] + p[2 * ZS] + p[3 * ZS];
    unsigned short vb = f2bf(v);
    long b_ = row >> 9, qi = row & 511;
    for (int h = h0; h < NHEAD; h += 4) {
      long idx = ((b_ * NHEAD + h) * KVTOT + 512 + qi) * QHD + 128 + j;
      kout[idx] = v;
      kb[idx] = vb;
    }
    return;
  }
  bool isQ = bid < 1024;
  int row = isQ ? bid : bid - 1024;
  int cols = isQ ? 1536 : 512;
  const float* g = isQ ? gq : gkv;
  unsigned short* out = isQ ? (qan + (long)row * 1536) : (ckvn + (long)row * 512);
  const float* x = part + (long)row * 2176 + (isQ ? 0 : 1536);
  int w = t >> 6, l = t & 63;
  float xv[6];
  int nc = cols >> 8;
  float ss = 0.f;
  for (int i = 0; i < nc; ++i) {
    int c = t + i * 256;
    float v = x[c] + x[c + ZS] + x[c + 2 * ZS] + x[c + 3 * ZS];
    xv[i] = v; ss += v * v;
  }
  #pragma unroll
  for (int m = 32; m >= 1; m >>= 1) ss += __shfl_xor(ss, m);
  __shared__ float red[4];
  if (l == 0) red[w] = ss;
  __syncthreads();
  float tot = red[0] + red[1] + red[2] + red[3];
  float rs = rsqrtf(tot / (float)cols + 1e-6f);
  for (int i = 0; i < nc; ++i) {
    int c = t + i * 256;
    out[c] = f2bf(g[c] * xv[i] * rs);
  }
}

// ---------------- merged Q-GEMM + KV-GEMM: 128x128 tile, BK=64, 4 waves ----------------
// 1D grid 3584, XCD-correct remap: the 8 row-tiles of one B-panel land on ONE XCD,
// consecutively dispatched -> B-panel fetched once into that XCD's L2.
// panel < 192: Q GEMM (A=qan,B=wqb,K=1536); else: KV GEMM (A=ckvn,B=wkvb,K=512).
// KV epilogue also writes Vt bf16 (transposed) directly for new rows.
__global__ __launch_bounds__(256, 4) void gemm_bt2(const unsigned short* __restrict__ Aq,
                                                   const unsigned short* __restrict__ Bq,
                                                   const unsigned short* __restrict__ Akv,
                                                   const unsigned short* __restrict__ Bkv,
                                                   unsigned short* __restrict__ qout,
                                                   float* __restrict__ kout,
                                                   float* __restrict__ vout,
                                                   unsigned short* __restrict__ kb,
                                                   unsigned short* __restrict__ vt) {
  __shared__ __align__(16) unsigned short sA[128 * 64];
  __shared__ __align__(16) unsigned short sB[128 * 64];
  const int t = threadIdx.x, w = t >> 6, l = t & 63;
  const int l15 = l & 15, lh = l >> 4;
  const int swz7 = l15 & 7;
  const int wm = w >> 1, wn = w & 1;
  // remap: xcd = id%8; panel = xcd + 8*(slot/8) in [0,448); row-tile = slot%8
  const int id = blockIdx.x;
  const int xcd = id & 7, slot = id >> 3;
  const int y = xcd + 8 * (slot >> 3);
  const int mb = slot & 7;
  const bool isQ = y < 192;
  const int nb = isQ ? y : y - 192;
  const int K = isQ ? QLORA : 512;
  const unsigned short* Ab = (isQ ? Aq : Akv) + (long)mb * 128 * K;
  const unsigned short* Bb = (isQ ? Bq : Bkv) + (long)nb * 128 * K;
  f32x4 acc[4][4];
  #pragma unroll
  for (int i = 0; i < 4; ++i)
    #pragma unroll
    for (int j = 0; j < 4; ++j)
      #pragma unroll
      for (int r = 0; r < 4; ++r) acc[i][j][r] = 0.f;

  const int srow = l >> 3;
  const int scol = ((l & 7) ^ srow) * 8;  // XOR-swizzled source chunk

  for (int kt = 0; kt < K; kt += 64) {
    #pragma unroll
    for (int i = 0; i < 4; ++i) {
      const int chunk = i * 4 + w;
      const int r = chunk * 8 + srow;
      g2l16(Ab + (long)r * K + kt + scol, (char*)sA + chunk * 1024);
      g2l16(Bb + (long)r * K + kt + scol, (char*)sB + chunk * 1024);
    }
    __syncthreads();
    #pragma unroll
    for (int ks = 0; ks < 2; ++ks) {
      bf16x8 af[4], bfr[4];
      #pragma unroll
      for (int i = 0; i < 4; ++i)
        af[i] = *(const bf16x8*)(sA + (wm * 64 + i * 16 + l15) * 64 + ((ks * 4 + lh) ^ swz7) * 8);
      #pragma unroll
      for (int j = 0; j < 4; ++j)
        bfr[j] = *(const bf16x8*)(sB + (wn * 64 + j * 16 + l15) * 64 + ((ks * 4 + lh) ^ swz7) * 8);
      #pragma unroll
      for (int i = 0; i < 4; ++i)
        #pragma unroll
        for (int j = 0; j < 4; ++j)
          acc[i][j] = __builtin_amdgcn_mfma_f32_16x16x32_bf16(af[i], bfr[j], acc[i][j], 0, 0, 0);
    }
    __syncthreads();
  }

  const long rowbase = (long)mb * 128 + wm * 64;
  const long b_ = rowbase >> 9;                 // whole 128-row tile is one b
  const int colbase = nb * 128 + wn * 64;
  #pragma unroll
  for (int i = 0; i < 4; ++i) {
    const long qi0 = (rowbase + i * 16 + lh * 4) & 511;
    #pragma unroll
    for (int j = 0; j < 4; ++j) {
      const int col = colbase + j * 16 + l15;
      if (isQ) {
        const int h = col / QHD, d = col - h * QHD;
        unsigned short* qp = qout + ((b_ * NHEAD + h) * QLEN + qi0) * QHD + d;
        #pragma unroll
        for (int r4 = 0; r4 < 4; ++r4) qp[(long)r4 * QHD] = f2bf(acc[i][j][r4]);
      } else {
        const int h = col >> 8, d = col & 255;
        if (d < 128) {
          const long idx = ((b_ * NHEAD + h) * KVTOT + 512 + qi0) * QHD + d;
          #pragma unroll
          for (int r4 = 0; r4 < 4; ++r4) {
            kout[idx + (long)r4 * QHD] = acc[i][j][r4];
            kb[idx + (long)r4 * QHD] = f2bf(acc[i][j][r4]);
          }
        } else {
          const int dv = d - 128;
          float* vp = vout + ((b_ * NHEAD + h) * KVTOT + 512 + qi0) * VHD + dv;
          u16x4 tv;
          #pragma unroll
          for (int r4 = 0; r4 < 4; ++r4) {
            vp[(long)r4 * VHD] = acc[i][j][r4];
            tv[r4] = f2bf(acc[i][j][r4]);
          }
          *(u16x4*)(vt + ((b_ * NHEAD + h) * VHD + dv) * KVTOT + 512 + qi0) = tv;
        }
      }
    }
  }
}

// ---------------- past key copy: f32 out + bf16 ws ----------------
__global__ __launch_bounds__(256) void copy_key_past_k(const float* __restrict__ pk,
                                                       float* __restrict__ kout,
                                                       unsigned short* __restrict__ kb) {
  long i4 = (long)blockIdx.x * 256 + threadIdx.x;
  f32x4 v = *(const f32x4*)(pk + i4 * 4);
  long e = i4 * 4;
  long bh = e / 98304;
  long rem = e - bh * 98304;
  long oidx = bh * 196608 + rem;
  *(f32x4*)(kout + oidx) = v;
  u16x4 b;
  b[0] = f2bf(v[0]); b[1] = f2bf(v[1]); b[2] = f2bf(v[2]); b[3] = f2bf(v[3]);
  *(u16x4*)(kb + oidx) = b;
}

// ---------------- V past rows only: copy pv -> out_val + transpose -> Vt bf16 ----------
__global__ __launch_bounds__(256) void vfix_k(const float* __restrict__ pv,
                                              float* __restrict__ outv,
                                              unsigned short* __restrict__ vt) {
  __shared__ __align__(16) unsigned short sT[128 * 72];
  int bh = blockIdx.x >> 3, kt = blockIdx.x & 7;  // past tiles: kv rows [kt*64, kt*64+64)
  int t = threadIdx.x;
  const float* src = pv + ((long)bh * 512 + kt * 64) * VHD;
  float* dstv = outv + ((long)bh * KVTOT + kt * 64) * VHD;
  #pragma unroll
  for (int i = 0; i < 8; ++i) {
    int id = t + i * 256;
    int r = id >> 5, c4 = (id & 31) * 4;
    f32x4 v = *(const f32x4*)(src + (long)r * VHD + c4);
    *(f32x4*)(dstv + (long)r * VHD + c4) = v;
    #pragma unroll
    for (int jj = 0; jj < 4; ++jj) sT[(c4 + jj) * 72 + r] = f2bf(v[jj]);
  }
  __syncthreads();
  #pragma unroll
  for (int i = 0; i < 4; ++i) {
    int id = t + i * 256;
    int d = id >> 3, c = id & 7;
    u16x8 v = *(const u16x8*)(sT + d * 72 + c * 8);
    *(u16x8*)(vt + ((long)bh * VHD + d) * KVTOT + kt * 64 + c * 8) = v;
  }
}

// ---------------- attention staging helpers (XOR-swizzled source, linear LDS dest) ----
static __device__ __forceinline__ void stage_k_tile(const unsigned short* __restrict__ src,
                                                    char* dstbase, int t) {
  const int w = t >> 6;
  #pragma unroll
  for (int i2 = 0; i2 < 6; ++i2) {
    int n = i2 * 256 + t;
    int r = n / 24, cp = n - r * 24;
    int c = cp ^ (r & 7);
    g2l16(src + (long)r * QHD + c * 8, dstbase + (i2 * 256 + w * 64) * 16);
  }
}

static __device__ __forceinline__ void stage_v_tile(const unsigned short* __restrict__ src,
                                                    char* dstbase, int t) {
  const int w = t >> 6;
  #pragma unroll
  for (int i2 = 0; i2 < 4; ++i2) {
    int n = i2 * 256 + t;
    int r = n >> 3, cp = n & 7;
    int c = cp ^ (r & 7);
    g2l16(src + (long)r * KVTOT + c * 8, dstbase + (i2 * 256 + w * 64) * 16);
  }
}

// ---------------- flash attention: 1 block = (b,h, 128-row q tile), 4 waves ----------------
// LDS 64 KB -> 2 blocks/CU. sP aliased into sK[cur]; 2 barriers/iter.
__global__ __launch_bounds__(256, 2) void attn_k(const unsigned short* __restrict__ Qw,
                                                 const unsigned short* __restrict__ Kb,
                                                 const unsigned short* __restrict__ Vt,
                                                 const float* __restrict__ mask,
                                                 const int* __restrict__ flags,
                                                 float* __restrict__ outp) {
  __shared__ __align__(16) unsigned short sK[2][64 * 192];
  __shared__ __align__(16) unsigned short sV[128 * 64];
  const int t = threadIdx.x, w = t >> 6, l = t & 63;
  const int l15 = l & 15, lh = l >> 4;
  const int raw = blockIdx.x;
  const int xcd = raw & 7, slot = raw >> 3;
  const int bh = xcd * 32 + (slot >> 2), qt = slot & 3;
  const long b_ = bh >> 7;
  const float SCALE = 0.051023330039633184f;
  const int swz = l15 & 7;

  bf16x8 qf[2][6];
  const unsigned short* Qb = Qw + ((long)bh * QLEN + qt * 128 + w * 32) * QHD;
  #pragma unroll
  for (int i = 0; i < 2; ++i)
    #pragma unroll
    for (int ks = 0; ks < 6; ++ks)
      qf[i][ks] = *(const bf16x8*)(Qb + (i * 16 + l15) * QHD + ks * 32 + lh * 8);

  f32x4 o[2][8];
  #pragma unroll
  for (int i = 0; i < 2; ++i)
    #pragma unroll
    for (int j = 0; j < 8; ++j)
      #pragma unroll
      for (int r = 0; r < 4; ++r) o[i][j][r] = 0.f;
  float m_[2][4], l_[2][4];  // l_ is a per-lane partial (reduced in epilogue)
  #pragma unroll
  for (int i = 0; i < 2; ++i)
    #pragma unroll
    for (int r = 0; r < 4; ++r) { m_[i][r] = -1e30f; l_[i][r] = 0.f; }

  const int qrow0 = qt * 128 + w * 32;
  const unsigned short* Kbh = Kb + (long)bh * KVTOT * QHD;
  const unsigned short* Vbh = Vt + (long)bh * VHD * KVTOT;
  const float* mrow = mask + b_ * 524288 + (long)(qrow0 + lh * 4) * 1024 + l15;
  const int fbase = (int)b_ * 64 + qt * 16;

  stage_k_tile(Kbh, (char*)sK[0], t);
  __syncthreads();

  for (int kt = 0; kt < 16; ++kt) {
    const int cur = kt & 1;
    stage_v_tile(Vbh + kt * 64, (char*)sV, t);
    if (kt < 15) stage_k_tile(Kbh + (long)(kt + 1) * 64 * QHD, (char*)sK[cur ^ 1], t);
    const int flag = flags[fbase + kt];

    const unsigned short* sKc = sK[cur];
    f32x4 s[2][4];
    #pragma unroll
    for (int i = 0; i < 2; ++i)
      #pragma unroll
      for (int j = 0; j < 4; ++j)
        #pragma unroll
        for (int r = 0; r < 4; ++r) s[i][j][r] = 0.f;
    __builtin_amdgcn_s_setprio(1);
    #pragma unroll
    for (int j = 0; j < 4; ++j) {
      #pragma unroll
      for (int ks = 0; ks < 6; ++ks) {
        bf16x8 kf = *(const bf16x8*)(sKc + ((j * 16 + l15) * 24 + ((ks * 4 + lh) ^ swz)) * 8);
        s[0][j] = __builtin_amdgcn_mfma_f32_16x16x32_bf16(qf[0][ks], kf, s[0][j], 0, 0, 0);
        s[1][j] = __builtin_amdgcn_mfma_f32_16x16x32_bf16(qf[1][ks], kf, s[1][j], 0, 0, 0);
      }
    }
    __builtin_amdgcn_s_setprio(0);

    unsigned short pk16[2][4][4];
    #pragma unroll
    for (int i = 0; i < 2; ++i) {
      #pragma unroll
      for (int rg = 0; rg < 4; ++rg) {
        float sc[4];
        if (flag) {
          #pragma unroll
          for (int j = 0; j < 4; ++j)
            sc[j] = s[i][j][rg] * SCALE + mrow[(long)(i * 16 + rg) * 1024 + kt * 64 + j * 16];
        } else {
          #pragma unroll
          for (int j = 0; j < 4; ++j) sc[j] = s[i][j][rg] * SCALE;
        }
        float mx = fmaxf(fmaxf(sc[0], sc[1]), fmaxf(sc[2], sc[3]));
        mx = fmaxf(mx, __shfl_xor(mx, 1));
        mx = fmaxf(mx, __shfl_xor(mx, 2));
        mx = fmaxf(mx, __shfl_xor(mx, 4));
        mx = fmaxf(mx, __shfl_xor(mx, 8));
        float mo = m_[i][rg];
        float mn = fmaxf(mo, mx);
        if (__any(mn > mo)) {
          float al = __expf(mo - mn);
          #pragma unroll
          for (int jj = 0; jj < 8; ++jj) o[i][jj][rg] *= al;
          l_[i][rg] *= al;
          m_[i][rg] = mn;
        }
        float ps = 0.f;
        #pragma unroll
        for (int j = 0; j < 4; ++j) {
          float p = __expf(sc[j] - m_[i][rg]);
          ps += p;
          pk16[i][rg][j] = f2bf(p);
        }
        l_[i][rg] += ps;
      }
    }
    __syncthreads();  // #1: QK^T reads of sK[cur] done; staged V (+next K) drained

    unsigned short* sPc = (unsigned short*)sK[cur];
    #pragma unroll
    for (int i = 0; i < 2; ++i)
      #pragma unroll
      for (int rg = 0; rg < 4; ++rg) {
        const int prow = w * 32 + i * 16 + lh * 4 + rg;
        #pragma unroll
        for (int j = 0; j < 4; ++j)
          sPc[prow * 72 + j * 16 + l15] = pk16[i][rg][j];
      }

    __builtin_amdgcn_s_setprio(1);
    #pragma unroll
    for (int ks = 0; ks < 2; ++ks) {
      bf16x8 pf0 = *(const bf16x8*)(sPc + (w * 32 + l15) * 72 + ks * 32 + lh * 8);
      bf16x8 pf1 = *(const bf16x8*)(sPc + (w * 32 + 16 + l15) * 72 + ks * 32 + lh * 8);
      #pragma unroll
      for (int jj = 0; jj < 8; ++jj) {
        bf16x8 vf = *(const bf16x8*)(sV + ((jj * 16 + l15) * 8 + ((ks * 4 + lh) ^ swz)) * 8);
        o[0][jj] = __builtin_amdgcn_mfma_f32_16x16x32_bf16(pf0, vf, o[0][jj], 0, 0, 0);
        o[1][jj] = __builtin_amdgcn_mfma_f32_16x16x32_bf16(pf1, vf, o[1][jj], 0, 0, 0);
      }
    }
    __builtin_amdgcn_s_setprio(0);
    __syncthreads();  // #2: PV done before next iter's stages overwrite sK[cur]/sV
  }

  #pragma unroll
  for (int i = 0; i < 2; ++i) {
    #pragma unroll
    for (int rg = 0; rg < 4; ++rg) {
      float ls = l_[i][rg];
      ls += __shfl_xor(ls, 1);
      ls += __shfl_xor(ls, 2);
      ls += __shfl_xor(ls, 4);
      ls += __shfl_xor(ls, 8);
      float inv = 1.0f / ls;
      long row = (long)bh * QLEN + qrow0 + i * 16 + lh * 4 + rg;
      #pragma unroll
      for (int jj = 0; jj < 8; ++jj)
        outp[row * VHD + jj * 16 + l15] = o[i][jj][rg] * inv;
    }
  }
}

// ---------------- workspace layout (bytes) ----------------
#define WS_HID_BF   0L           // 1024x5120 bf16            = 10,485,760
#define WS_WQA_BF   10485760L    // stacked [wqa;wkva;pad] 2176x5120 bf16 = 22,282,240
#define WS_WQB_BF   32768000L    // 24576x1536 bf16           = 75,497,472
#define WS_WKVB_BF  108265472L   // 32768x512 bf16            = 33,554,432
#define WS_QAN_BF   141819904L   // 1024x1536 bf16            =  3,145,728
#define WS_CKVN_BF  144965632L   // 1024x512 bf16             =  1,048,576
#define WS_Q_BF     146014208L   // 50,331,648 (part f32 35.6MB aliased here first)
#define WS_KB_BF    196345856L   // 100,663,296
#define WS_VT_BF    297009152L   // 67,108,864
#define WS_FLAGS    364118016L   // 512
// total ~364.1 MB

extern "C" void kernel_launch(void* const* d_in, const int* in_sizes, int n_in,
                              void* d_out, int out_size, void* d_ws, size_t ws_size,
                              hipStream_t stream) {
  const float* hs   = (const float*)d_in[0];
  const float* mask = (const float*)d_in[1];
  const float* pk   = (const float*)d_in[2];
  const float* pv   = (const float*)d_in[3];
  const float* wqa  = (const float*)d_in[4];
  const float* gqa  = (const float*)d_in[5];
  const float* wqb  = (const float*)d_in[6];
  const float* wkva = (const float*)d_in[7];
  const float* gkva = (const float*)d_in[8];
  const float* wkvb = (const float*)d_in[9];

  char* ws = (char*)d_ws;
  unsigned short* hid_bf  = (unsigned short*)(ws + WS_HID_BF);
  unsigned short* wqa_bf  = (unsigned short*)(ws + WS_WQA_BF);  // stacked [wqa;wkva;pad]
  unsigned short* wkva_bf = wqa_bf + (long)1536 * 5120;
  unsigned short* wqb_bf  = (unsigned short*)(ws + WS_WQB_BF);
  unsigned short* wkvb_bf = (unsigned short*)(ws + WS_WKVB_BF);
  unsigned short* qan_bf  = (unsigned short*)(ws + WS_QAN_BF);
  unsigned short* ckvn_bf = (unsigned short*)(ws + WS_CKVN_BF);
  unsigned short* q_bf    = (unsigned short*)(ws + WS_Q_BF);
  float*          part    = (float*)(ws + WS_Q_BF);  // aliased: dead before q_bf written
  unsigned short* kb_bf   = (unsigned short*)(ws + WS_KB_BF);
  unsigned short* vt_bf   = (unsigned short*)(ws + WS_VT_BF);
  int*            flags   = (int*)(ws + WS_FLAGS);

  float* out_attn = (float*)d_out;
  float* out_key  = (float*)d_out + 16777216;
  float* out_val  = (float*)d_out + 67108864;

  // 0. mask zero-flags
  flags_k<<<128, 256, 0, stream>>>(mask, flags);
  // 1. zero the 64 pad rows of stacked wkva, then all converts in one kernel
  hipMemsetAsync(ws + WS_WQA_BF + (long)2112 * 5120 * 2, 0, (long)64 * 5120 * 2, stream);
  CvtArgs ca;
  ca.src[0] = hs;     ca.dst[0] = hid_bf;
  ca.src[1] = wqa;    ca.dst[1] = wqa_bf;
  ca.src[2] = wkva;   ca.dst[2] = wkva_bf;
  ca.src[3] = wqb;    ca.dst[3] = wqb_bf;
  ca.src[4] = wkvb;   ca.dst[4] = wkvb_bf;
  ca.off[0] = 0; ca.off[1] = 1280; ca.off[2] = 3200; ca.off[3] = 3920;
  ca.off[4] = 13136; ca.off[5] = 17232;
  cvt_all_k<<<17232, 256, 0, stream>>>(ca);
  // 2. past key copy (independent)
  copy_key_past_k<<<24576, 256, 0, stream>>>(pk, out_key, kb_bf);
  // 3. fused q_a + ckv GEMM, split-K(4) -> part  (XCD-remapped 1D grid)
  gemm_qa_ckv<<<1088, 256, 0, stream>>>(hid_bf, wqa_bf, part);
  // 4. fused rmsnorms + k_pe broadcast (sums partials)
  post_a_k<<<3072, 256, 0, stream>>>(part, gqa, gkva, qan_bf, ckvn_bf, out_key, kb_bf);
  // 5. merged Q-GEMM + KV-GEMM (XCD-remapped 1D grid; writes Vt for new rows)
  gemm_bt2<<<3584, 256, 0, stream>>>(qan_bf, wqb_bf, ckvn_bf, wkvb_bf,
                                     q_bf, out_key, out_val, kb_bf, vt_bf);
  // 6. V past rows: copy + transpose -> Vt bf16
  vfix_k<<<2048, 256, 0, stream>>>(pv, out_val, vt_bf);
  // 7. attention
  attn_k<<<1024, 256, 0, stream>>>(q_bf, kb_bf, vt_bf, mask, flags, out_attn);
}

// Round 7
// 577.560 us; speedup vs baseline: 1.4807x; 1.0017x over previous
//
#include <hip/hip_runtime.h>

// ---------------- problem constants ----------------
#define NB    2
#define QLEN  512
#define HIDD  5120
#define QLORA 1536
#define NHEAD 128
#define QHD   192
#define VHD   128
#define KVTOT 1024

typedef float          f32x4   __attribute__((ext_vector_type(4)));
typedef __bf16         bf16x8  __attribute__((ext_vector_type(8)));
typedef unsigned short u16x8   __attribute__((ext_vector_type(8)));
typedef unsigned short u16x4   __attribute__((ext_vector_type(4)));

static __device__ __forceinline__ unsigned short f2bf(float f) {
  union { float f; unsigned u; } v; v.f = f;
  return (unsigned short)((v.u + 0x7fffu + ((v.u >> 16) & 1u)) >> 16);
}

static __device__ __forceinline__ void g2l16(const void* g, void* l) {
  __builtin_amdgcn_global_load_lds(
      (const __attribute__((address_space(1))) void*)g,
      (__attribute__((address_space(3))) void*)l, 16, 0, 0);
}

// ---------------- zero the 64 pad rows of stacked wkva (640 KB) ----------------
__global__ __launch_bounds__(256) void zero_pad_k(unsigned short* __restrict__ dst) {
  int i = blockIdx.x * 256 + threadIdx.x;   // 160*256 = 40960 threads, 16 B each
  u16x8 z = {0, 0, 0, 0, 0, 0, 0, 0};
  *(u16x8*)(dst + (long)i * 8) = z;
}

// ---------------- merged f32 -> bf16 converts (5 segments) ----------------
struct CvtArgs {
  const float* src[5];
  unsigned short* dst[5];
  int off[6];  // cumulative block offsets; each block = 1024 f32x4
};

__global__ __launch_bounds__(256) void cvt_all_k(CvtArgs a) {
  int b = blockIdx.x, s = 0;
  #pragma unroll
  for (int k = 0; k < 4; ++k) if (b >= a.off[k + 1]) s = k + 1;
  long lb = b - a.off[s];
  const float* in = a.src[s];
  unsigned short* out = a.dst[s];
  long base = lb * 1024 + threadIdx.x;
  #pragma unroll
  for (int k = 0; k < 4; ++k) {
    long i = base + k * 256;
    f32x4 v = *(const f32x4*)(in + i * 4);
    u16x4 o;
    o[0] = f2bf(v[0]); o[1] = f2bf(v[1]); o[2] = f2bf(v[2]); o[3] = f2bf(v[3]);
    *(u16x4*)(out + i * 4) = o;
  }
}

// ---------------- mask zero-flags: 1 flag per (b, 128-qtile, 64-ktile) ----------------
__global__ __launch_bounds__(256) void flags_k(const float* __restrict__ mask,
                                               int* __restrict__ flags) {
  int id = blockIdx.x;  // b*64 + qt*16 + kt
  int b = id >> 6, qt = (id >> 4) & 3, kt = id & 15;
  const float* base = mask + (long)b * 524288 + (long)qt * 128 * 1024 + kt * 64;
  int t = threadIdx.x, w = t >> 6;
  unsigned acc = 0;
  #pragma unroll
  for (int i = 0; i < 32; ++i) {
    int e = i * 256 + t;
    int r = e >> 6, c = e & 63;
    union { float f; unsigned u; } v; v.f = base[(long)r * 1024 + c];
    acc |= v.u;
  }
  int any = __any(acc != 0);
  __shared__ int sf[4];
  if ((t & 63) == 0) sf[w] = any;
  __syncthreads();
  if (t == 0) flags[id] = sf[0] | sf[1] | sf[2] | sf[3];
}

// ---------------- fused q_a + ckv GEMM, split-K(4): 128x64 tile, 4 waves ----------------
// 1D grid 1088, XCD-correct remap: all 8 row-tiles of a (panel,z) on ONE XCD.
// B = [w_q_a (1536 rows) ; w_kv_a (576 rows) ; 64 zero rows], rows K-contig.
// writes f32 partials: part[(z*1024 + row)*2176 + col]
__global__ __launch_bounds__(256, 4) void gemm_qa_ckv(const unsigned short* __restrict__ A,
                                                      const unsigned short* __restrict__ Bm,
                                                      float* __restrict__ part) {
  __shared__ __align__(16) unsigned short sA[128 * 64];
  __shared__ __align__(16) unsigned short sB[64 * 64];
  const int t = threadIdx.x, w = t >> 6, l = t & 63;
  const int l15 = l & 15, lh = l >> 4;
  const int swz7 = l15 & 7;
  // remap: xcd = id%8; panel-z index pz = xcd + 8*(slot/8) in [0,136); row-tile = slot%8
  const int id = blockIdx.x;
  const int xcd = id & 7, slot = id >> 3;
  const int pz = xcd + 8 * (slot >> 3);
  const int mb = slot & 7;
  const int z = pz / 34;
  const int nb = pz - z * 34;
  const unsigned short* Ab = A + (long)mb * 128 * HIDD;
  const unsigned short* Bb = Bm + (long)nb * 64 * HIDD;
  f32x4 acc[2][4];
  #pragma unroll
  for (int i = 0; i < 2; ++i)
    #pragma unroll
    for (int j = 0; j < 4; ++j)
      #pragma unroll
      for (int r = 0; r < 4; ++r) acc[i][j][r] = 0.f;

  const int k0 = z * 1280;
  for (int kt = k0; kt < k0 + 1280; kt += 64) {
    #pragma unroll
    for (int i2 = 0; i2 < 4; ++i2) {
      int n = i2 * 256 + t, r = n >> 3, c = (n & 7) ^ (r & 7);
      g2l16(Ab + (long)r * HIDD + kt + c * 8, (char*)sA + (i2 * 256 + w * 64) * 16);
    }
    #pragma unroll
    for (int i2 = 0; i2 < 2; ++i2) {
      int n = i2 * 256 + t, r = n >> 3, c = (n & 7) ^ (r & 7);
      g2l16(Bb + (long)r * HIDD + kt + c * 8, (char*)sB + (i2 * 256 + w * 64) * 16);
    }
    __syncthreads();
    #pragma unroll
    for (int ks = 0; ks < 2; ++ks) {
      bf16x8 af[2], bfr[4];
      #pragma unroll
      for (int i = 0; i < 2; ++i)
        af[i] = *(const bf16x8*)(sA + (w * 32 + i * 16 + l15) * 64 + ((ks * 4 + lh) ^ swz7) * 8);
      #pragma unroll
      for (int j = 0; j < 4; ++j)
        bfr[j] = *(const bf16x8*)(sB + (j * 16 + l15) * 64 + ((ks * 4 + lh) ^ swz7) * 8);
      #pragma unroll
      for (int i = 0; i < 2; ++i)
        #pragma unroll
        for (int j = 0; j < 4; ++j)
          acc[i][j] = __builtin_amdgcn_mfma_f32_16x16x32_bf16(af[i], bfr[j], acc[i][j], 0, 0, 0);
    }
    __syncthreads();
  }
  float* po = part + (long)z * 1024 * 2176;
  const int colbase = nb * 64;
  #pragma unroll
  for (int i = 0; i < 2; ++i)
    #pragma unroll
    for (int j = 0; j < 4; ++j) {
      const int col = colbase + j * 16 + l15;
      #pragma unroll
      for (int r4 = 0; r4 < 4; ++r4) {
        const long row = (long)mb * 128 + w * 32 + i * 16 + lh * 4 + r4;
        po[row * 2176 + col] = acc[i][j][r4];
      }
    }
}

// ---------------- fused rmsnorm(q_a) + rmsnorm(ckv) + k_pe broadcast ----------------
__global__ __launch_bounds__(256) void post_a_k(const float* __restrict__ part,
                                                const float* __restrict__ gq,
                                                const float* __restrict__ gkv,
                                                unsigned short* __restrict__ qan,
                                                unsigned short* __restrict__ ckvn,
                                                float* __restrict__ kout,
                                                unsigned short* __restrict__ kb) {
  const long ZS = 1024L * 2176;
  int bid = blockIdx.x, t = threadIdx.x;
  if (bid >= 2048) {  // k_pe broadcast
    int row = bid - 2048;
    int j = t & 63, h0 = t >> 6;
    const float* p = part + (long)row * 2176 + 2048 + j;
    float v = p[0] + p[ZS] + p[2 * ZS] + p[3 * ZS];
    unsigned short vb = f2bf(v);
    long b_ = row >> 9, qi = row & 511;
    for (int h = h0; h < NHEAD; h += 4) {
      long idx = ((b_ * NHEAD + h) * KVTOT + 512 + qi) * QHD + 128 + j;
      kout[idx] = v;
      kb[idx] = vb;
    }
    return;
  }
  bool isQ = bid < 1024;
  int row = isQ ? bid : bid - 1024;
  int cols = isQ ? 1536 : 512;
  const float* g = isQ ? gq : gkv;
  unsigned short* out = isQ ? (qan + (long)row * 1536) : (ckvn + (long)row * 512);
  const float* x = part + (long)row * 2176 + (isQ ? 0 : 1536);
  int w = t >> 6, l = t & 63;
  float xv[6];
  int nc = cols >> 8;
  float ss = 0.f;
  for (int i = 0; i < nc; ++i) {
    int c = t + i * 256;
    float v = x[c] + x[c + ZS] + x[c + 2 * ZS] + x[c + 3 * ZS];
    xv[i] = v; ss += v * v;
  }
  #pragma unroll
  for (int m = 32; m >= 1; m >>= 1) ss += __shfl_xor(ss, m);
  __shared__ float red[4];
  if (l == 0) red[w] = ss;
  __syncthreads();
  float tot = red[0] + red[1] + red[2] + red[3];
  float rs = rsqrtf(tot / (float)cols + 1e-6f);
  for (int i = 0; i < nc; ++i) {
    int c = t + i * 256;
    out[c] = f2bf(g[c] * xv[i] * rs);
  }
}

// ---------------- merged Q-GEMM + KV-GEMM: 128x128 tile, BK=64, 4 waves ----------------
// 1D grid 3584, XCD-correct remap: the 8 row-tiles of one B-panel land on ONE XCD,
// consecutively dispatched -> B-panel fetched once into that XCD's L2.
// panel < 192: Q GEMM (A=qan,B=wqb,K=1536); else: KV GEMM (A=ckvn,B=wkvb,K=512).
// KV epilogue also writes Vt bf16 (transposed) directly for new rows.
__global__ __launch_bounds__(256, 4) void gemm_bt2(const unsigned short* __restrict__ Aq,
                                                   const unsigned short* __restrict__ Bq,
                                                   const unsigned short* __restrict__ Akv,
                                                   const unsigned short* __restrict__ Bkv,
                                                   unsigned short* __restrict__ qout,
                                                   float* __restrict__ kout,
                                                   float* __restrict__ vout,
                                                   unsigned short* __restrict__ kb,
                                                   unsigned short* __restrict__ vt) {
  __shared__ __align__(16) unsigned short sA[128 * 64];
  __shared__ __align__(16) unsigned short sB[128 * 64];
  const int t = threadIdx.x, w = t >> 6, l = t & 63;
  const int l15 = l & 15, lh = l >> 4;
  const int swz7 = l15 & 7;
  const int wm = w >> 1, wn = w & 1;
  // remap: xcd = id%8; panel = xcd + 8*(slot/8) in [0,448); row-tile = slot%8
  const int id = blockIdx.x;
  const int xcd = id & 7, slot = id >> 3;
  const int y = xcd + 8 * (slot >> 3);
  const int mb = slot & 7;
  const bool isQ = y < 192;
  const int nb = isQ ? y : y - 192;
  const int K = isQ ? QLORA : 512;
  const unsigned short* Ab = (isQ ? Aq : Akv) + (long)mb * 128 * K;
  const unsigned short* Bb = (isQ ? Bq : Bkv) + (long)nb * 128 * K;
  f32x4 acc[4][4];
  #pragma unroll
  for (int i = 0; i < 4; ++i)
    #pragma unroll
    for (int j = 0; j < 4; ++j)
      #pragma unroll
      for (int r = 0; r < 4; ++r) acc[i][j][r] = 0.f;

  const int srow = l >> 3;
  const int scol = ((l & 7) ^ srow) * 8;  // XOR-swizzled source chunk

  for (int kt = 0; kt < K; kt += 64) {
    #pragma unroll
    for (int i = 0; i < 4; ++i) {
      const int chunk = i * 4 + w;
      const int r = chunk * 8 + srow;
      g2l16(Ab + (long)r * K + kt + scol, (char*)sA + chunk * 1024);
      g2l16(Bb + (long)r * K + kt + scol, (char*)sB + chunk * 1024);
    }
    __syncthreads();
    #pragma unroll
    for (int ks = 0; ks < 2; ++ks) {
      bf16x8 af[4], bfr[4];
      #pragma unroll
      for (int i = 0; i < 4; ++i)
        af[i] = *(const bf16x8*)(sA + (wm * 64 + i * 16 + l15) * 64 + ((ks * 4 + lh) ^ swz7) * 8);
      #pragma unroll
      for (int j = 0; j < 4; ++j)
        bfr[j] = *(const bf16x8*)(sB + (wn * 64 + j * 16 + l15) * 64 + ((ks * 4 + lh) ^ swz7) * 8);
      #pragma unroll
      for (int i = 0; i < 4; ++i)
        #pragma unroll
        for (int j = 0; j < 4; ++j)
          acc[i][j] = __builtin_amdgcn_mfma_f32_16x16x32_bf16(af[i], bfr[j], acc[i][j], 0, 0, 0);
    }
    __syncthreads();
  }

  const long rowbase = (long)mb * 128 + wm * 64;
  const long b_ = rowbase >> 9;                 // whole 128-row tile is one b
  const int colbase = nb * 128 + wn * 64;
  #pragma unroll
  for (int i = 0; i < 4; ++i) {
    const long qi0 = (rowbase + i * 16 + lh * 4) & 511;
    #pragma unroll
    for (int j = 0; j < 4; ++j) {
      const int col = colbase + j * 16 + l15;
      if (isQ) {
        const int h = col / QHD, d = col - h * QHD;
        unsigned short* qp = qout + ((b_ * NHEAD + h) * QLEN + qi0) * QHD + d;
        #pragma unroll
        for (int r4 = 0; r4 < 4; ++r4) qp[(long)r4 * QHD] = f2bf(acc[i][j][r4]);
      } else {
        const int h = col >> 8, d = col & 255;
        if (d < 128) {
          const long idx = ((b_ * NHEAD + h) * KVTOT + 512 + qi0) * QHD + d;
          #pragma unroll
          for (int r4 = 0; r4 < 4; ++r4) {
            kout[idx + (long)r4 * QHD] = acc[i][j][r4];
            kb[idx + (long)r4 * QHD] = f2bf(acc[i][j][r4]);
          }
        } else {
          const int dv = d - 128;
          float* vp = vout + ((b_ * NHEAD + h) * KVTOT + 512 + qi0) * VHD + dv;
          u16x4 tv;
          #pragma unroll
          for (int r4 = 0; r4 < 4; ++r4) {
            vp[(long)r4 * VHD] = acc[i][j][r4];
            tv[r4] = f2bf(acc[i][j][r4]);
          }
          *(u16x4*)(vt + ((b_ * NHEAD + h) * VHD + dv) * KVTOT + 512 + qi0) = tv;
        }
      }
    }
  }
}

// ---------------- past key copy: f32 out + bf16 ws ----------------
__global__ __launch_bounds__(256) void copy_key_past_k(const float* __restrict__ pk,
                                                       float* __restrict__ kout,
                                                       unsigned short* __restrict__ kb) {
  long i4 = (long)blockIdx.x * 256 + threadIdx.x;
  f32x4 v = *(const f32x4*)(pk + i4 * 4);
  long e = i4 * 4;
  long bh = e / 98304;
  long rem = e - bh * 98304;
  long oidx = bh * 196608 + rem;
  *(f32x4*)(kout + oidx) = v;
  u16x4 b;
  b[0] = f2bf(v[0]); b[1] = f2bf(v[1]); b[2] = f2bf(v[2]); b[3] = f2bf(v[3]);
  *(u16x4*)(kb + oidx) = b;
}

// ---------------- V past rows only: copy pv -> out_val + transpose -> Vt bf16 ----------
__global__ __launch_bounds__(256) void vfix_k(const float* __restrict__ pv,
                                              float* __restrict__ outv,
                                              unsigned short* __restrict__ vt) {
  __shared__ __align__(16) unsigned short sT[128 * 72];
  int bh = blockIdx.x >> 3, kt = blockIdx.x & 7;  // past tiles: kv rows [kt*64, kt*64+64)
  int t = threadIdx.x;
  const float* src = pv + ((long)bh * 512 + kt * 64) * VHD;
  float* dstv = outv + ((long)bh * KVTOT + kt * 64) * VHD;
  #pragma unroll
  for (int i = 0; i < 8; ++i) {
    int id = t + i * 256;
    int r = id >> 5, c4 = (id & 31) * 4;
    f32x4 v = *(const f32x4*)(src + (long)r * VHD + c4);
    *(f32x4*)(dstv + (long)r * VHD + c4) = v;
    #pragma unroll
    for (int jj = 0; jj < 4; ++jj) sT[(c4 + jj) * 72 + r] = f2bf(v[jj]);
  }
  __syncthreads();
  #pragma unroll
  for (int i = 0; i < 4; ++i) {
    int id = t + i * 256;
    int d = id >> 3, c = id & 7;
    u16x8 v = *(const u16x8*)(sT + d * 72 + c * 8);
    *(u16x8*)(vt + ((long)bh * VHD + d) * KVTOT + kt * 64 + c * 8) = v;
  }
}

// ---------------- attention staging helpers (XOR-swizzled source, linear LDS dest) ----
static __device__ __forceinline__ void stage_k_tile(const unsigned short* __restrict__ src,
                                                    char* dstbase, int t) {
  const int w = t >> 6;
  #pragma unroll
  for (int i2 = 0; i2 < 6; ++i2) {
    int n = i2 * 256 + t;
    int r = n / 24, cp = n - r * 24;
    int c = cp ^ (r & 7);
    g2l16(src + (long)r * QHD + c * 8, dstbase + (i2 * 256 + w * 64) * 16);
  }
}

static __device__ __forceinline__ void stage_v_tile(const unsigned short* __restrict__ src,
                                                    char* dstbase, int t) {
  const int w = t >> 6;
  #pragma unroll
  for (int i2 = 0; i2 < 4; ++i2) {
    int n = i2 * 256 + t;
    int r = n >> 3, cp = n & 7;
    int c = cp ^ (r & 7);
    g2l16(src + (long)r * KVTOT + c * 8, dstbase + (i2 * 256 + w * 64) * 16);
  }
}

// ---------------- flash attention: 1 block = (b,h, 128-row q tile), 4 waves ----------------
// LDS 64 KB -> 2 blocks/CU. sP aliased into sK[cur]; 2 barriers/iter.
__global__ __launch_bounds__(256, 2) void attn_k(const unsigned short* __restrict__ Qw,
                                                 const unsigned short* __restrict__ Kb,
                                                 const unsigned short* __restrict__ Vt,
                                                 const float* __restrict__ mask,
                                                 const int* __restrict__ flags,
                                                 float* __restrict__ outp) {
  __shared__ __align__(16) unsigned short sK[2][64 * 192];
  __shared__ __align__(16) unsigned short sV[128 * 64];
  const int t = threadIdx.x, w = t >> 6, l = t & 63;
  const int l15 = l & 15, lh = l >> 4;
  const int raw = blockIdx.x;
  const int xcd = raw & 7, slot = raw >> 3;
  const int bh = xcd * 32 + (slot >> 2), qt = slot & 3;
  const long b_ = bh >> 7;
  const float SCALE = 0.051023330039633184f;
  const int swz = l15 & 7;

  bf16x8 qf[2][6];
  const unsigned short* Qb = Qw + ((long)bh * QLEN + qt * 128 + w * 32) * QHD;
  #pragma unroll
  for (int i = 0; i < 2; ++i)
    #pragma unroll
    for (int ks = 0; ks < 6; ++ks)
      qf[i][ks] = *(const bf16x8*)(Qb + (i * 16 + l15) * QHD + ks * 32 + lh * 8);

  f32x4 o[2][8];
  #pragma unroll
  for (int i = 0; i < 2; ++i)
    #pragma unroll
    for (int j = 0; j < 8; ++j)
      #pragma unroll
      for (int r = 0; r < 4; ++r) o[i][j][r] = 0.f;
  float m_[2][4], l_[2][4];  // l_ is a per-lane partial (reduced in epilogue)
  #pragma unroll
  for (int i = 0; i < 2; ++i)
    #pragma unroll
    for (int r = 0; r < 4; ++r) { m_[i][r] = -1e30f; l_[i][r] = 0.f; }

  const int qrow0 = qt * 128 + w * 32;
  const unsigned short* Kbh = Kb + (long)bh * KVTOT * QHD;
  const unsigned short* Vbh = Vt + (long)bh * VHD * KVTOT;
  const float* mrow = mask + b_ * 524288 + (long)(qrow0 + lh * 4) * 1024 + l15;
  const int fbase = (int)b_ * 64 + qt * 16;

  stage_k_tile(Kbh, (char*)sK[0], t);
  __syncthreads();

  for (int kt = 0; kt < 16; ++kt) {
    const int cur = kt & 1;
    stage_v_tile(Vbh + kt * 64, (char*)sV, t);
    if (kt < 15) stage_k_tile(Kbh + (long)(kt + 1) * 64 * QHD, (char*)sK[cur ^ 1], t);
    const int flag = flags[fbase + kt];

    const unsigned short* sKc = sK[cur];
    f32x4 s[2][4];
    #pragma unroll
    for (int i = 0; i < 2; ++i)
      #pragma unroll
      for (int j = 0; j < 4; ++j)
        #pragma unroll
        for (int r = 0; r < 4; ++r) s[i][j][r] = 0.f;
    __builtin_amdgcn_s_setprio(1);
    #pragma unroll
    for (int j = 0; j < 4; ++j) {
      #pragma unroll
      for (int ks = 0; ks < 6; ++ks) {
        bf16x8 kf = *(const bf16x8*)(sKc + ((j * 16 + l15) * 24 + ((ks * 4 + lh) ^ swz)) * 8);
        s[0][j] = __builtin_amdgcn_mfma_f32_16x16x32_bf16(qf[0][ks], kf, s[0][j], 0, 0, 0);
        s[1][j] = __builtin_amdgcn_mfma_f32_16x16x32_bf16(qf[1][ks], kf, s[1][j], 0, 0, 0);
      }
    }
    __builtin_amdgcn_s_setprio(0);

    unsigned short pk16[2][4][4];
    #pragma unroll
    for (int i = 0; i < 2; ++i) {
      #pragma unroll
      for (int rg = 0; rg < 4; ++rg) {
        float sc[4];
        if (flag) {
          #pragma unroll
          for (int j = 0; j < 4; ++j)
            sc[j] = s[i][j][rg] * SCALE + mrow[(long)(i * 16 + rg) * 1024 + kt * 64 + j * 16];
        } else {
          #pragma unroll
          for (int j = 0; j < 4; ++j) sc[j] = s[i][j][rg] * SCALE;
        }
        float mx = fmaxf(fmaxf(sc[0], sc[1]), fmaxf(sc[2], sc[3]));
        mx = fmaxf(mx, __shfl_xor(mx, 1));
        mx = fmaxf(mx, __shfl_xor(mx, 2));
        mx = fmaxf(mx, __shfl_xor(mx, 4));
        mx = fmaxf(mx, __shfl_xor(mx, 8));
        float mo = m_[i][rg];
        float mn = fmaxf(mo, mx);
        if (__any(mn > mo)) {
          float al = __expf(mo - mn);
          #pragma unroll
          for (int jj = 0; jj < 8; ++jj) o[i][jj][rg] *= al;
          l_[i][rg] *= al;
          m_[i][rg] = mn;
        }
        float ps = 0.f;
        #pragma unroll
        for (int j = 0; j < 4; ++j) {
          float p = __expf(sc[j] - m_[i][rg]);
          ps += p;
          pk16[i][rg][j] = f2bf(p);
        }
        l_[i][rg] += ps;
      }
    }
    __syncthreads();  // #1: QK^T reads of sK[cur] done; staged V (+next K) drained

    unsigned short* sPc = (unsigned short*)sK[cur];
    #pragma unroll
    for (int i = 0; i < 2; ++i)
      #pragma unroll
      for (int rg = 0; rg < 4; ++rg) {
        const int prow = w * 32 + i * 16 + lh * 4 + rg;
        #pragma unroll
        for (int j = 0; j < 4; ++j)
          sPc[prow * 72 + j * 16 + l15] = pk16[i][rg][j];
      }

    __builtin_amdgcn_s_setprio(1);
    #pragma unroll
    for (int ks = 0; ks < 2; ++ks) {
      bf16x8 pf0 = *(const bf16x8*)(sPc + (w * 32 + l15) * 72 + ks * 32 + lh * 8);
      bf16x8 pf1 = *(const bf16x8*)(sPc + (w * 32 + 16 + l15) * 72 + ks * 32 + lh * 8);
      #pragma unroll
      for (int jj = 0; jj < 8; ++jj) {
        bf16x8 vf = *(const bf16x8*)(sV + ((jj * 16 + l15) * 8 + ((ks * 4 + lh) ^ swz)) * 8);
        o[0][jj] = __builtin_amdgcn_mfma_f32_16x16x32_bf16(pf0, vf, o[0][jj], 0, 0, 0);
        o[1][jj] = __builtin_amdgcn_mfma_f32_16x16x32_bf16(pf1, vf, o[1][jj], 0, 0, 0);
      }
    }
    __builtin_amdgcn_s_setprio(0);
    __syncthreads();  // #2: PV done before next iter's stages overwrite sK[cur]/sV
  }

  #pragma unroll
  for (int i = 0; i < 2; ++i) {
    #pragma unroll
    for (int rg = 0; rg < 4; ++rg) {
      float ls = l_[i][rg];
      ls += __shfl_xor(ls, 1);
      ls += __shfl_xor(ls, 2);
      ls += __shfl_xor(ls, 4);
      ls += __shfl_xor(ls, 8);
      float inv = 1.0f / ls;
      long row = (long)bh * QLEN + qrow0 + i * 16 + lh * 4 + rg;
      #pragma unroll
      for (int jj = 0; jj < 8; ++jj)
        outp[row * VHD + jj * 16 + l15] = o[i][jj][rg] * inv;
    }
  }
}

// ---------------- workspace layout (bytes) ----------------
#define WS_HID_BF   0L           // 1024x5120 bf16            = 10,485,760
#define WS_WQA_BF   10485760L    // stacked [wqa;wkva;pad] 2176x5120 bf16 = 22,282,240
#define WS_WQB_BF   32768000L    // 24576x1536 bf16           = 75,497,472
#define WS_WKVB_BF  108265472L   // 32768x512 bf16            = 33,554,432
#define WS_QAN_BF   141819904L   // 1024x1536 bf16            =  3,145,728
#define WS_CKVN_BF  144965632L   // 1024x512 bf16             =  1,048,576
#define WS_Q_BF     146014208L   // 50,331,648 (part f32 35.6MB aliased here first)
#define WS_KB_BF    196345856L   // 100,663,296
#define WS_VT_BF    297009152L   // 67,108,864
#define WS_FLAGS    364118016L   // 512
// total ~364.1 MB

extern "C" void kernel_launch(void* const* d_in, const int* in_sizes, int n_in,
                              void* d_out, int out_size, void* d_ws, size_t ws_size,
                              hipStream_t stream) {
  const float* hs   = (const float*)d_in[0];
  const float* mask = (const float*)d_in[1];
  const float* pk   = (const float*)d_in[2];
  const float* pv   = (const float*)d_in[3];
  const float* wqa  = (const float*)d_in[4];
  const float* gqa  = (const float*)d_in[5];
  const float* wqb  = (const float*)d_in[6];
  const float* wkva = (const float*)d_in[7];
  const float* gkva = (const float*)d_in[8];
  const float* wkvb = (const float*)d_in[9];

  char* ws = (char*)d_ws;
  unsigned short* hid_bf  = (unsigned short*)(ws + WS_HID_BF);
  unsigned short* wqa_bf  = (unsigned short*)(ws + WS_WQA_BF);  // stacked [wqa;wkva;pad]
  unsigned short* wkva_bf = wqa_bf + (long)1536 * 5120;
  unsigned short* wpad_bf = wqa_bf + (long)2112 * 5120;
  unsigned short* wqb_bf  = (unsigned short*)(ws + WS_WQB_BF);
  unsigned short* wkvb_bf = (unsigned short*)(ws + WS_WKVB_BF);
  unsigned short* qan_bf  = (unsigned short*)(ws + WS_QAN_BF);
  unsigned short* ckvn_bf = (unsigned short*)(ws + WS_CKVN_BF);
  unsigned short* q_bf    = (unsigned short*)(ws + WS_Q_BF);
  float*          part    = (float*)(ws + WS_Q_BF);  // aliased: dead before q_bf written
  unsigned short* kb_bf   = (unsigned short*)(ws + WS_KB_BF);
  unsigned short* vt_bf   = (unsigned short*)(ws + WS_VT_BF);
  int*            flags   = (int*)(ws + WS_FLAGS);

  float* out_attn = (float*)d_out;
  float* out_key  = (float*)d_out + 16777216;
  float* out_val  = (float*)d_out + 67108864;

  // 0. mask zero-flags + pad-row zeroing (replaces the 230us fillBufferAligned!)
  flags_k<<<128, 256, 0, stream>>>(mask, flags);
  zero_pad_k<<<160, 256, 0, stream>>>(wpad_bf);
  // 1. all converts in one kernel
  CvtArgs ca;
  ca.src[0] = hs;     ca.dst[0] = hid_bf;
  ca.src[1] = wqa;    ca.dst[1] = wqa_bf;
  ca.src[2] = wkva;   ca.dst[2] = wkva_bf;
  ca.src[3] = wqb;    ca.dst[3] = wqb_bf;
  ca.src[4] = wkvb;   ca.dst[4] = wkvb_bf;
  ca.off[0] = 0; ca.off[1] = 1280; ca.off[2] = 3200; ca.off[3] = 3920;
  ca.off[4] = 13136; ca.off[5] = 17232;
  cvt_all_k<<<17232, 256, 0, stream>>>(ca);
  // 2. past key copy (independent)
  copy_key_past_k<<<24576, 256, 0, stream>>>(pk, out_key, kb_bf);
  // 3. fused q_a + ckv GEMM, split-K(4) -> part  (XCD-remapped 1D grid)
  gemm_qa_ckv<<<1088, 256, 0, stream>>>(hid_bf, wqa_bf, part);
  // 4. fused rmsnorms + k_pe broadcast (sums partials)
  post_a_k<<<3072, 256, 0, stream>>>(part, gqa, gkva, qan_bf, ckvn_bf, out_key, kb_bf);
  // 5. merged Q-GEMM + KV-GEMM (XCD-remapped 1D grid; writes Vt for new rows)
  gemm_bt2<<<3584, 256, 0, stream>>>(qan_bf, wqb_bf, ckvn_bf, wkvb_bf,
                                     q_bf, out_key, out_val, kb_bf, vt_bf);
  // 6. V past rows: copy + transpose -> Vt bf16
  vfix_k<<<2048, 256, 0, stream>>>(pv, out_val, vt_bf);
  // 7. attention
  attn_k<<<1024, 256, 0, stream>>>(q_bf, kb_bf, vt_bf, mask, flags, out_attn);
}